// Round 2
// baseline (1024.933 us; speedup 1.0000x reference)
//
#include <hip/hip_runtime.h>
#include <math.h>

#define B_ 16
#define C_ 256
#define N_ 2048
#define D_ 64

// ---------------- workspace layout (floats) ----------------
// ~50.6 MB total. Y lives in d_out (same shape as the final output and dead
// before bn_apply overwrites it). H aliases Qt/Kt/V which are dead by then.
static constexpr size_t SZ_QT = (size_t)B_ * D_ * N_;      // 2,097,152
static constexpr size_t SZ_V  = (size_t)B_ * N_ * C_;      // 8,388,608
static constexpr size_t OFF_QT = 0;
static constexpr size_t OFF_KT = OFF_QT + SZ_QT;
static constexpr size_t OFF_V  = OFF_KT + SZ_QT;
static constexpr size_t OFF_CM = OFF_V + SZ_V;             // colmax  [B*N]
static constexpr size_t OFF_CD = OFF_CM + (size_t)B_ * N_; // 1/denom [B*N]
static constexpr size_t OFF_S1 = OFF_CD + (size_t)B_ * N_;
static constexpr size_t OFF_S2 = OFF_S1 + C_;
static constexpr size_t OFF_AB = OFF_S2 + C_;              // A[256], B[256]
static constexpr size_t OFF_H  = 0;                        // aliases QT/KT/V

// ---------------- generic 64x64-tile GEMM: out = W(rows x C) * X[b] ----------------
// X: [B][C_][N_]; W: [orowsTotal][C_], row window = blockIdx.z*64
// TSTORE=false: out[b][orow][n] (row-major, stride N_)
// TSTORE=true : out[b][n][orow] (for V: [B][N][C])
// STATS=true  : atomicAdd per-channel sum / sumsq of outputs into s1g/s2g
template <bool TSTORE, bool STATS>
__global__ __launch_bounds__(256, 2) void gemm64_kernel(
    const float* __restrict__ X, const float* __restrict__ W,
    float* __restrict__ out, const int orowsTotal,
    float* __restrict__ s1g, float* __restrict__ s2g) {
  __shared__ alignas(16) float wL[64][68];  // [c][o]
  __shared__ alignas(16) float xL[64][68];  // [c][n]
  __shared__ float red[STATS ? 2048 : 4];
  const int tid = threadIdx.x;
  const int b = blockIdx.y;
  const int n0 = blockIdx.x * 64;
  const int obase = blockIdx.z * 64;
  const int og4 = (tid & 15) * 4;
  const int ng = tid >> 4;
  const int ng4 = ng * 4;
  float acc[4][4] = {};
  const float* Xb = X + (size_t)b * C_ * N_ + n0;
  for (int cc = 0; cc < C_; cc += 64) {
    __syncthreads();
#pragma unroll
    for (int k = 0; k < 16; ++k) {
      int i = tid + k * 256;
      int hi = i >> 6, lo = i & 63;
      wL[lo][hi] = W[(size_t)(obase + hi) * C_ + cc + lo];   // transpose to [c][o]
      xL[hi][lo] = Xb[(size_t)(cc + hi) * N_ + lo];          // [c][n]
    }
    __syncthreads();
#pragma unroll
    for (int c = 0; c < 64; ++c) {
      float4 wv = *reinterpret_cast<const float4*>(&wL[c][og4]);
      float4 xv = *reinterpret_cast<const float4*>(&xL[c][ng4]);
      float wa[4] = {wv.x, wv.y, wv.z, wv.w};
      float xa[4] = {xv.x, xv.y, xv.z, xv.w};
#pragma unroll
      for (int i = 0; i < 4; ++i)
#pragma unroll
        for (int j = 0; j < 4; ++j) acc[i][j] += wa[i] * xa[j];
    }
  }
  if (TSTORE) {
#pragma unroll
    for (int j = 0; j < 4; ++j) {
      float4 v = make_float4(acc[0][j], acc[1][j], acc[2][j], acc[3][j]);
      *reinterpret_cast<float4*>(
          &out[((size_t)b * N_ + n0 + ng4 + j) * C_ + obase + og4]) = v;
    }
  } else {
#pragma unroll
    for (int i = 0; i < 4; ++i) {
      float4 v = make_float4(acc[i][0], acc[i][1], acc[i][2], acc[i][3]);
      *reinterpret_cast<float4*>(
          &out[((size_t)b * orowsTotal + obase + og4 + i) * N_ + n0 + ng4]) = v;
    }
  }
  if (STATS) {
#pragma unroll
    for (int i = 0; i < 4; ++i) {
      float l1 = 0.f, l2 = 0.f;
#pragma unroll
      for (int j = 0; j < 4; ++j) {
        l1 += acc[i][j];
        l2 += acc[i][j] * acc[i][j];
      }
      red[(og4 + i) * 16 + ng] = l1;
      red[1024 + (og4 + i) * 16 + ng] = l2;
    }
    __syncthreads();
    if (tid < 64) {
      float t1 = 0.f, t2 = 0.f;
#pragma unroll
      for (int g = 0; g < 16; ++g) {
        t1 += red[tid * 16 + g];
        t2 += red[1024 + tid * 16 + g];
      }
      atomicAdd(&s1g[obase + tid], t1);
      atomicAdd(&s2g[obase + tid], t2);
    }
  }
}

// ---------------- pass 1: column softmax stats (softmax over query axis n) ----------
// S[n][m] = sum_d Qt[b][d][n] * Kt[b][d][m]; per (b,m): max_n and sum_n exp(S-max)
__global__ __launch_bounds__(256, 2) void colstats_kernel(
    const float* __restrict__ Qt, const float* __restrict__ Kt,
    float* __restrict__ cmax, float* __restrict__ cinv) {
  __shared__ alignas(16) float kb[64][68];  // [d][m]
  __shared__ alignas(16) float qn[64][68];  // [d][n]
  __shared__ float rmx[1024];
  __shared__ float rsm[1024];
  const int tid = threadIdx.x;
  const int b = blockIdx.y;
  const int m0 = blockIdx.x * 64;
  const int mg4 = (tid & 15) * 4;
  const int ngr = tid >> 4;
  const int ng4 = ngr * 4;
  const float* Ktb = Kt + (size_t)b * D_ * N_;
  const float* Qtb = Qt + (size_t)b * D_ * N_;
#pragma unroll
  for (int k = 0; k < 16; ++k) {
    int i = tid + k * 256;
    int d = i >> 6, ml = i & 63;
    kb[d][ml] = Ktb[(size_t)d * N_ + m0 + ml];
  }
  float mx[4] = {-INFINITY, -INFINITY, -INFINITY, -INFINITY};
  float sm[4] = {0.f, 0.f, 0.f, 0.f};
  for (int nc = 0; nc < N_; nc += 64) {
    __syncthreads();
#pragma unroll
    for (int k = 0; k < 16; ++k) {
      int i = tid + k * 256;
      int d = i >> 6, nl = i & 63;
      qn[d][nl] = Qtb[(size_t)d * N_ + nc + nl];
    }
    __syncthreads();
    float s[4][4] = {};
#pragma unroll
    for (int d = 0; d < 64; ++d) {
      float4 kv = *reinterpret_cast<const float4*>(&kb[d][mg4]);
      float4 qv = *reinterpret_cast<const float4*>(&qn[d][ng4]);
      float ka[4] = {kv.x, kv.y, kv.z, kv.w};
      float qa[4] = {qv.x, qv.y, qv.z, qv.w};
#pragma unroll
      for (int i = 0; i < 4; ++i)
#pragma unroll
        for (int j = 0; j < 4; ++j) s[i][j] += ka[i] * qa[j];
    }
#pragma unroll
    for (int i = 0; i < 4; ++i) {
#pragma unroll
      for (int j = 0; j < 4; ++j) {
        float v = s[i][j];
        if (v > mx[i]) {
          sm[i] *= __expf(mx[i] - v);
          mx[i] = v;
        }
        sm[i] += __expf(v - mx[i]);
      }
    }
  }
#pragma unroll
  for (int i = 0; i < 4; ++i) {
    rmx[(mg4 + i) * 16 + ngr] = mx[i];
    rsm[(mg4 + i) * 16 + ngr] = sm[i];
  }
  __syncthreads();
  if (tid < 64) {
    float M = -INFINITY;
#pragma unroll
    for (int g = 0; g < 16; ++g) M = fmaxf(M, rmx[tid * 16 + g]);
    float S = 0.f;
#pragma unroll
    for (int g = 0; g < 16; ++g) S += rsm[tid * 16 + g] * __expf(rmx[tid * 16 + g] - M);
    cmax[(size_t)b * N_ + m0 + tid] = M;
    cinv[(size_t)b * N_ + m0 + tid] = 1.f / S;
  }
}

// ---------------- pass 2: fused attention + fsa + y = x - fsa ----------------
__global__ __launch_bounds__(256, 2) void attn_fsa_kernel(
    const float* __restrict__ x, const float* __restrict__ Qt,
    const float* __restrict__ Kt, const float* __restrict__ V,
    const float* __restrict__ cmax, const float* __restrict__ cinv,
    float* __restrict__ Y) {
  __shared__ alignas(16) float qt[64][68];  // [d][n], staged once
  __shared__ alignas(16) float kb[64][68];  // [d][m], per chunk
  __shared__ alignas(16) float pt[64][68];  // p[m][n], per chunk
  __shared__ float rch[1024];               // [mg(16)][n(64)]
  __shared__ float racc[64];
  __shared__ float cmS[64], cdS[64];
  const int tid = threadIdx.x;
  const int b = blockIdx.y;
  const int n0 = blockIdx.x * 64;
  const float* Qtb = Qt + (size_t)b * D_ * N_;
  const float* Ktb = Kt + (size_t)b * D_ * N_;
  const float* Vb = V + (size_t)b * N_ * C_;
  const int mg = tid & 15;
  const int mg4 = mg * 4;
  const int ng4 = (tid >> 4) * 4;
  const int oc8 = (tid & 31) * 8;
  const int nc8 = (tid >> 5) * 8;
#pragma unroll
  for (int k = 0; k < 16; ++k) {
    int i = tid + k * 256;
    int d = i >> 6, nl = i & 63;
    qt[d][nl] = Qtb[(size_t)d * N_ + n0 + nl];
  }
  if (tid < 64) racc[tid] = 0.f;
  float acc[8][8] = {};  // [o_i][n_j]
  for (int mc = 0; mc < N_; mc += 64) {
    __syncthreads();
#pragma unroll
    for (int k = 0; k < 16; ++k) {
      int i = tid + k * 256;
      int d = i >> 6, ml = i & 63;
      kb[d][ml] = Ktb[(size_t)d * N_ + mc + ml];
    }
    if (tid < 64) {
      cmS[tid] = cmax[(size_t)b * N_ + mc + tid];
      cdS[tid] = cinv[(size_t)b * N_ + mc + tid];
    }
    __syncthreads();
    // --- S tile (4m x 4n per thread) ---
    float s[4][4] = {};
#pragma unroll
    for (int d = 0; d < 64; ++d) {
      float4 kv = *reinterpret_cast<const float4*>(&kb[d][mg4]);
      float4 qv = *reinterpret_cast<const float4*>(&qt[d][ng4]);
      float ka[4] = {kv.x, kv.y, kv.z, kv.w};
      float qa[4] = {qv.x, qv.y, qv.z, qv.w};
#pragma unroll
      for (int i = 0; i < 4; ++i)
#pragma unroll
        for (int j = 0; j < 4; ++j) s[i][j] += ka[i] * qa[j];
    }
    // --- p = exp(S - colmax)*cinv; stage to LDS; partial row-sums ---
    float rloc[4] = {0.f, 0.f, 0.f, 0.f};
#pragma unroll
    for (int i = 0; i < 4; ++i) {
      float cm = cmS[mg4 + i], cd = cdS[mg4 + i];
      float p0 = __expf(s[i][0] - cm) * cd;
      float p1 = __expf(s[i][1] - cm) * cd;
      float p2 = __expf(s[i][2] - cm) * cd;
      float p3 = __expf(s[i][3] - cm) * cd;
      rloc[0] += p0; rloc[1] += p1; rloc[2] += p2; rloc[3] += p3;
      *reinterpret_cast<float4*>(&pt[mg4 + i][ng4]) = make_float4(p0, p1, p2, p3);
    }
#pragma unroll
    for (int j = 0; j < 4; ++j) rch[mg * 64 + ng4 + j] = rloc[j];
    __syncthreads();
    if (tid < 64) {
      float r = 0.f;
#pragma unroll
      for (int g = 0; g < 16; ++g) r += rch[g * 64 + tid];
      racc[tid] += r;
    }
    // --- fsa accumulate: acc[o_i][n_j] += V[m][o] * p[m][n] ---
    const float* Vm = Vb + (size_t)mc * C_ + oc8;
#pragma unroll 2
    for (int m = 0; m < 64; ++m) {
      float4 v0 = *reinterpret_cast<const float4*>(&Vm[(size_t)m * C_]);
      float4 v1 = *reinterpret_cast<const float4*>(&Vm[(size_t)m * C_ + 4]);
      float4 p0 = *reinterpret_cast<const float4*>(&pt[m][nc8]);
      float4 p1 = *reinterpret_cast<const float4*>(&pt[m][nc8 + 4]);
      float va[8] = {v0.x, v0.y, v0.z, v0.w, v1.x, v1.y, v1.z, v1.w};
      float pa[8] = {p0.x, p0.y, p0.z, p0.w, p1.x, p1.y, p1.z, p1.w};
#pragma unroll
      for (int i = 0; i < 8; ++i)
#pragma unroll
        for (int j = 0; j < 8; ++j) acc[i][j] += va[i] * pa[j];
    }
  }
  __syncthreads();
  float rinv[8];
#pragma unroll
  for (int j = 0; j < 8; ++j) rinv[j] = 1.f / (1e-9f + racc[nc8 + j]);
  const float* xb = x + (size_t)b * C_ * N_ + n0;
  float* Yb = Y + (size_t)b * C_ * N_ + n0;
#pragma unroll
  for (int i = 0; i < 8; ++i) {
    int o = oc8 + i;
    const float* xr = xb + (size_t)o * N_ + nc8;
    float* yr = Yb + (size_t)o * N_ + nc8;
    float4 x0 = *reinterpret_cast<const float4*>(&xr[0]);
    float4 x1 = *reinterpret_cast<const float4*>(&xr[4]);
    float4 y0 = make_float4(x0.x - acc[i][0] * rinv[0], x0.y - acc[i][1] * rinv[1],
                            x0.z - acc[i][2] * rinv[2], x0.w - acc[i][3] * rinv[3]);
    float4 y1 = make_float4(x1.x - acc[i][4] * rinv[4], x1.y - acc[i][5] * rinv[5],
                            x1.z - acc[i][6] * rinv[6], x1.w - acc[i][7] * rinv[7]);
    *reinterpret_cast<float4*>(&yr[0]) = y0;
    *reinterpret_cast<float4*>(&yr[4]) = y1;
  }
}

// ---------------- BN finalize + fused epilogue ----------------
__global__ void bn_final_kernel(const float* __restrict__ s1,
                                const float* __restrict__ s2,
                                const float* __restrict__ gamma,
                                const float* __restrict__ beta,
                                float* __restrict__ AB) {
  int o = threadIdx.x;
  const float invn = 1.f / ((float)B_ * N_);
  float mean = s1[o] * invn;
  float var = s2[o] * invn - mean * mean;
  float inv = rsqrtf(var + 1e-5f);
  float A = gamma[o] * inv;
  AB[o] = A;
  AB[256 + o] = beta[o] - mean * A;
}

__global__ __launch_bounds__(256) void bn_apply_kernel(
    const float* __restrict__ H, const float* __restrict__ x,
    const float* __restrict__ AB, float* __restrict__ out) {
  size_t idx = ((size_t)blockIdx.x * 256 + threadIdx.x) * 4;
  int o = (int)((idx >> 11) & 255);
  float a = AB[o], c = AB[256 + o];
  float4 h = *reinterpret_cast<const float4*>(&H[idx]);
  float4 xv = *reinterpret_cast<const float4*>(&x[idx]);
  float4 r;
  r.x = fmaxf(h.x * a + c, 0.f) + xv.x;
  r.y = fmaxf(h.y * a + c, 0.f) + xv.y;
  r.z = fmaxf(h.z * a + c, 0.f) + xv.z;
  r.w = fmaxf(h.w * a + c, 0.f) + xv.w;
  *reinterpret_cast<float4*>(&out[idx]) = r;
}

extern "C" void kernel_launch(void* const* d_in, const int* in_sizes, int n_in,
                              void* d_out, int out_size, void* d_ws, size_t ws_size,
                              hipStream_t stream) {
  (void)in_sizes; (void)n_in; (void)out_size; (void)ws_size;
  const float* x = (const float*)d_in[0];
  const float* Wq = (const float*)d_in[1];
  const float* Wk = (const float*)d_in[2];
  const float* Wv = (const float*)d_in[3];
  const float* Wp = (const float*)d_in[4];
  const float* gamma = (const float*)d_in[5];
  const float* beta = (const float*)d_in[6];
  float* ws = (float*)d_ws;
  float* Qt = ws + OFF_QT;
  float* Kt = ws + OFF_KT;
  float* V = ws + OFF_V;
  float* CM = ws + OFF_CM;
  float* CD = ws + OFF_CD;
  float* S1 = ws + OFF_S1;
  float* S2 = ws + OFF_S2;
  float* AB = ws + OFF_AB;
  float* H = ws + OFF_H;
  float* out = (float*)d_out;
  float* Y = out;  // stage y = x - fsa in d_out; dead before bn_apply overwrites

  hipMemsetAsync(S1, 0, 2 * C_ * sizeof(float), stream);  // zeroes S1+S2

  dim3 blk(256);
  gemm64_kernel<false, false><<<dim3(32, 16, 1), blk, 0, stream>>>(x, Wq, Qt, 64, nullptr, nullptr);
  gemm64_kernel<false, false><<<dim3(32, 16, 1), blk, 0, stream>>>(x, Wk, Kt, 64, nullptr, nullptr);
  gemm64_kernel<true, false><<<dim3(32, 16, 4), blk, 0, stream>>>(x, Wv, V, 256, nullptr, nullptr);
  colstats_kernel<<<dim3(32, 16), blk, 0, stream>>>(Qt, Kt, CM, CD);
  attn_fsa_kernel<<<dim3(32, 16), blk, 0, stream>>>(x, Qt, Kt, V, CM, CD, Y);
  gemm64_kernel<false, true><<<dim3(32, 16, 4), blk, 0, stream>>>(Y, Wp, H, 256, S1, S2);
  bn_final_kernel<<<1, 256, 0, stream>>>(S1, S2, gamma, beta, AB);
  bn_apply_kernel<<<dim3(8192), blk, 0, stream>>>(H, x, AB, out);
}

// Round 3
// 1008.756 us; speedup vs baseline: 1.0160x; 1.0160x over previous
//
#include <hip/hip_runtime.h>
#include <math.h>

#define B_ 16
#define C_ 256
#define N_ 2048
#define D_ 64

typedef __attribute__((ext_vector_type(8))) short bf8;  // 8 bf16 (4 VGPRs)
typedef __attribute__((ext_vector_type(4))) float f4;   // MFMA C/D

#define MFMA16(A, Bv, Cv) __builtin_amdgcn_mfma_f32_16x16x32_bf16(A, Bv, Cv, 0, 0, 0)

__device__ __forceinline__ short f2b(float f) {  // f32 -> bf16 RNE
  unsigned u = __float_as_uint(f);
  u = (u + 0x7fff + ((u >> 16) & 1)) >> 16;
  return (short)u;
}
__device__ __forceinline__ float b2f(short s) {
  return __uint_as_float(((unsigned)(unsigned short)s) << 16);
}

// ---------------- workspace layout (bytes), ~40.5 MB ----------------
// xT region is reused for yT (xT dead after projections; yT written in pass 2).
static constexpr size_t OFF_XT = 0;                          // bf16 [B][N][C] 16 MB (later yT)
static constexpr size_t OFF_QN = (size_t)16 << 20;           // bf16 [B][N][64] 4 MB
static constexpr size_t OFF_KN = (size_t)20 << 20;           // bf16 [B][N][64] 4 MB
static constexpr size_t OFF_VT = (size_t)24 << 20;           // bf16 [B][C][N] 16 MB
static constexpr size_t OFF_CI = (size_t)40 << 20;           // f32 [B][N] 128 KB
static constexpr size_t OFF_WQ = OFF_CI + ((size_t)128 << 10);
static constexpr size_t OFF_WK = OFF_WQ + ((size_t)32 << 10);
static constexpr size_t OFF_WV = OFF_WK + ((size_t)32 << 10);
static constexpr size_t OFF_WP = OFF_WV + ((size_t)128 << 10);
static constexpr size_t OFF_S1 = OFF_WP + ((size_t)128 << 10);
static constexpr size_t OFF_S2 = OFF_S1 + 1024;
static constexpr size_t OFF_AB = OFF_S2 + 1024;

// ---------------- pack weights to bf16 ----------------
__global__ void pack_w_kernel(const float* __restrict__ q, const float* __restrict__ k,
                              const float* __restrict__ v, const float* __restrict__ p,
                              short* wq, short* wk, short* wv, short* wp) {
  int idx = blockIdx.x * 256 + threadIdx.x;
  int which = blockIdx.y;
  const float* s = which == 0 ? q : which == 1 ? k : which == 2 ? v : p;
  short* d = which == 0 ? wq : which == 1 ? wk : which == 2 ? wv : wp;
  int cnt = which < 2 ? 64 * 256 : 256 * 256;
  if (idx < cnt) d[idx] = f2b(s[idx]);
}

// ---------------- x [B][C][N] f32 -> xT [B][N][C] bf16 ----------------
__global__ __launch_bounds__(256) void transpose_x_kernel(const float* __restrict__ x,
                                                          short* __restrict__ xT) {
  __shared__ float t[64][65];
  const int b = blockIdx.z, c0 = blockIdx.y * 64, n0 = blockIdx.x * 64;
  const int tid = threadIdx.x;
  const float* xp = x + ((size_t)b * C_ + c0) * N_ + n0;
#pragma unroll
  for (int i = 0; i < 16; ++i) {
    int idx = tid + i * 256;
    int cl = idx >> 6, nl = idx & 63;
    t[cl][nl] = xp[(size_t)cl * N_ + nl];
  }
  __syncthreads();
  short* op = xT + ((size_t)b * N_ + n0) * C_ + c0;
#pragma unroll
  for (int i = 0; i < 8; ++i) {
    int idx = tid + i * 256;  // 2048 ushort2 pairs
    int nl = idx >> 5, cl2 = (idx & 31) * 2;
    ushort2 v;
    v.x = (unsigned short)f2b(t[cl2][nl]);
    v.y = (unsigned short)f2b(t[cl2 + 1][nl]);
    *(ushort2*)(op + (size_t)nl * C_ + cl2) = v;
  }
}

// ---------------- projection GEMM: out = W(OxC) . x[b]  (MFMA, no LDS) ----------------
// OUTT=true : out[b][n][O] (for Qn/Kn, O=64);  OUTT=false: out[b][o][N] (for Vt, O=256)
template <bool OUTT>
__global__ __launch_bounds__(256, 4) void proj_kernel(const short* __restrict__ xT,
                                                      const short* __restrict__ W,
                                                      short* __restrict__ out, const int O) {
  const int tid = threadIdx.x;
  const int wv = tid >> 6, lane = tid & 63;
  const int li = lane & 15, quad = lane >> 4;
  const int b = blockIdx.y, n0 = blockIdx.x * 64, o0 = blockIdx.z * 64;
  const int n = n0 + wv * 16 + li;
  const short* xrow = xT + ((size_t)b * N_ + n) * C_ + quad * 8;
  f4 acc[4] = {};
  for (int ks = 0; ks < 8; ++ks) {
    bf8 bfr = *(const bf8*)(xrow + ks * 32);
#pragma unroll
    for (int ot = 0; ot < 4; ++ot) {
      bf8 afr = *(const bf8*)(W + (size_t)(o0 + ot * 16 + li) * C_ + ks * 32 + quad * 8);
      acc[ot] = MFMA16(afr, bfr, acc[ot]);
    }
  }
  if (OUTT) {
#pragma unroll
    for (int ot = 0; ot < 4; ++ot) {
      short4 v = {f2b(acc[ot].x), f2b(acc[ot].y), f2b(acc[ot].z), f2b(acc[ot].w)};
      *(short4*)(out + ((size_t)b * N_ + n) * O + o0 + ot * 16 + quad * 4) = v;
    }
  } else {
#pragma unroll
    for (int ot = 0; ot < 4; ++ot) {
#pragma unroll
      for (int r = 0; r < 4; ++r) {
        out[((size_t)b * C_ + o0 + ot * 16 + quad * 4 + r) * N_ + n] = f2b(acc[ot][r]);
      }
    }
  }
}

// ---------------- pass 1: cinv[b][m] = 1 / sum_n exp(energy[n][m]) ----------------
// S'[m][n] = sum_d Kn[m][d]*Qn[n][d]; no max subtraction (|S| << 88, exp safe in f32)
__global__ __launch_bounds__(256, 4) void colstats_kernel(const short* __restrict__ Qn,
                                                          const short* __restrict__ Kn,
                                                          float* __restrict__ cinv) {
  const int tid = threadIdx.x;
  const int wv = tid >> 6, lane = tid & 63;
  const int li = lane & 15, quad = lane >> 4;
  const int b = blockIdx.y, m0 = blockIdx.x * 64;
  const short* krow = Kn + ((size_t)b * N_ + m0 + wv * 16 + li) * D_ + quad * 8;
  bf8 af0 = *(const bf8*)(krow);
  bf8 af1 = *(const bf8*)(krow + 32);
  const short* qbase = Qn + ((size_t)b * N_ + li) * D_ + quad * 8;
  float csum[4] = {0.f, 0.f, 0.f, 0.f};
#pragma unroll 4
  for (int ns = 0; ns < N_; ns += 16) {
    const short* qrow = qbase + (size_t)ns * D_;
    bf8 b0 = *(const bf8*)(qrow);
    bf8 b1 = *(const bf8*)(qrow + 32);
    f4 s = {};
    s = MFMA16(af0, b0, s);
    s = MFMA16(af1, b1, s);
    csum[0] += __expf(s.x);
    csum[1] += __expf(s.y);
    csum[2] += __expf(s.z);
    csum[3] += __expf(s.w);
  }
#pragma unroll
  for (int r = 0; r < 4; ++r) {
#pragma unroll
    for (int m = 1; m < 16; m <<= 1) csum[r] += __shfl_xor(csum[r], m);
  }
  if (li == 0) {
#pragma unroll
    for (int r = 0; r < 4; ++r)
      cinv[(size_t)b * N_ + m0 + wv * 16 + quad * 4 + r] = 1.f / csum[r];
  }
}

// ---------------- pass 2: attention + fsa + y = x - fsa (-> yT bf16) ----------------
__global__ __launch_bounds__(256, 2) void attn_fsa_kernel(
    const float* __restrict__ x, const short* __restrict__ Qn, const short* __restrict__ Kn,
    const short* __restrict__ Vt, const float* __restrict__ cinv, short* __restrict__ yT) {
  __shared__ short pT[64][72];  // P[m][n] stored transposed: pT[n][m], pitch 72 (144 B, 16B-mult)
  const int tid = threadIdx.x;
  const int wv = tid >> 6, lane = tid & 63;
  const int li = lane & 15, quad = lane >> 4;
  const int b = blockIdx.y, n0 = blockIdx.x * 64;
  const int nl = wv * 16 + li;  // local n (0..63), per-wave stripe
  const int n = n0 + nl;
  const short* qrow = Qn + ((size_t)b * N_ + n) * D_ + quad * 8;
  bf8 q0 = *(const bf8*)(qrow);       // loop-invariant Q B-frags
  bf8 q1 = *(const bf8*)(qrow + 32);
  const float* civ = cinv + (size_t)b * N_;
  f4 acc[16] = {};  // fsa: 256 o x 16 n (this lane's column li)
  float rsum = 0.f;
  for (int mc = 0; mc < N_; mc += 64) {
    __syncthreads();  // pT consumed by previous PV
#pragma unroll
    for (int mt = 0; mt < 4; ++mt) {
      const short* krow = Kn + ((size_t)b * N_ + mc + mt * 16 + li) * D_ + quad * 8;
      bf8 a0 = *(const bf8*)(krow);
      bf8 a1 = *(const bf8*)(krow + 32);
      f4 s = {};
      s = MFMA16(a0, q0, s);
      s = MFMA16(a1, q1, s);
      short4 pv;
#pragma unroll
      for (int r = 0; r < 4; ++r) {
        float p = __expf(s[r]) * civ[mc + mt * 16 + quad * 4 + r];
        short ph = f2b(p);
        ((short*)&pv)[r] = ph;
        rsum += b2f(ph);  // accumulate the bf16-rounded value for num/denom consistency
      }
      *(short4*)&pT[nl][mt * 16 + quad * 4] = pv;  // 8B write, 4 consecutive m
    }
    __syncthreads();
#pragma unroll
    for (int kf = 0; kf < 2; ++kf) {
      bf8 pb = *(const bf8*)&pT[nl][kf * 32 + quad * 8];  // B-frag: 8 consecutive m at row n
#pragma unroll
      for (int ot = 0; ot < 16; ++ot) {
        bf8 va = *(const bf8*)(Vt + ((size_t)b * C_ + ot * 16 + li) * N_ + mc + kf * 32 + quad * 8);
        acc[ot] = MFMA16(va, pb, acc[ot]);
      }
    }
  }
  rsum += __shfl_xor(rsum, 16);
  rsum += __shfl_xor(rsum, 32);
  const float rinv = 1.f / (1e-9f + rsum);
  short* yrow = yT + ((size_t)b * N_ + n) * C_;
#pragma unroll
  for (int ot = 0; ot < 16; ++ot) {
    short4 v;
#pragma unroll
    for (int r = 0; r < 4; ++r) {
      int o = ot * 16 + quad * 4 + r;
      float xv = x[((size_t)b * C_ + o) * N_ + n];
      ((short*)&v)[r] = f2b(xv - acc[ot][r] * rinv);
    }
    *(short4*)(yrow + ot * 16 + quad * 4) = v;
  }
}

// ---------------- h = Wp . y  -> H (=d_out) f32, + BN channel stats ----------------
__global__ __launch_bounds__(256, 4) void wp_kernel(const short* __restrict__ yT,
                                                    const short* __restrict__ Wp,
                                                    float* __restrict__ H,
                                                    float* __restrict__ s1g,
                                                    float* __restrict__ s2g) {
  const int tid = threadIdx.x;
  const int wv = tid >> 6, lane = tid & 63;
  const int li = lane & 15, quad = lane >> 4;
  const int b = blockIdx.y, n0 = blockIdx.x * 64, o0 = blockIdx.z * 64;
  const int n = n0 + wv * 16 + li;
  const short* yrow = yT + ((size_t)b * N_ + n) * C_ + quad * 8;
  f4 acc[4] = {};
  for (int ks = 0; ks < 8; ++ks) {
    bf8 bfr = *(const bf8*)(yrow + ks * 32);
#pragma unroll
    for (int ot = 0; ot < 4; ++ot) {
      bf8 afr = *(const bf8*)(Wp + (size_t)(o0 + ot * 16 + li) * C_ + ks * 32 + quad * 8);
      acc[ot] = MFMA16(afr, bfr, acc[ot]);
    }
  }
#pragma unroll
  for (int ot = 0; ot < 4; ++ot) {
#pragma unroll
    for (int r = 0; r < 4; ++r) {
      float h = acc[ot][r];
      H[((size_t)b * C_ + o0 + ot * 16 + quad * 4 + r) * N_ + n] = h;
      float l1 = h, l2 = h * h;
#pragma unroll
      for (int m2 = 1; m2 < 16; m2 <<= 1) {
        l1 += __shfl_xor(l1, m2);
        l2 += __shfl_xor(l2, m2);
      }
      if (li == 0) {
        atomicAdd(&s1g[o0 + ot * 16 + quad * 4 + r], l1);
        atomicAdd(&s2g[o0 + ot * 16 + quad * 4 + r], l2);
      }
    }
  }
}

// ---------------- BN finalize + fused epilogue ----------------
__global__ void bn_final_kernel(const float* __restrict__ s1, const float* __restrict__ s2,
                                const float* __restrict__ gamma, const float* __restrict__ beta,
                                float* __restrict__ AB) {
  int o = threadIdx.x;
  const float invn = 1.f / ((float)B_ * N_);
  float mean = s1[o] * invn;
  float var = s2[o] * invn - mean * mean;
  float inv = rsqrtf(var + 1e-5f);
  float A = gamma[o] * inv;
  AB[o] = A;
  AB[256 + o] = beta[o] - mean * A;
}

__global__ __launch_bounds__(256) void bn_apply_kernel(const float* __restrict__ H,
                                                       const float* __restrict__ x,
                                                       const float* __restrict__ AB,
                                                       float* __restrict__ out) {
  size_t idx = ((size_t)blockIdx.x * 256 + threadIdx.x) * 4;
  int o = (int)((idx >> 11) & 255);
  float a = AB[o], c = AB[256 + o];
  float4 h = *reinterpret_cast<const float4*>(&H[idx]);
  float4 xv = *reinterpret_cast<const float4*>(&x[idx]);
  float4 r;
  r.x = fmaxf(h.x * a + c, 0.f) + xv.x;
  r.y = fmaxf(h.y * a + c, 0.f) + xv.y;
  r.z = fmaxf(h.z * a + c, 0.f) + xv.z;
  r.w = fmaxf(h.w * a + c, 0.f) + xv.w;
  *reinterpret_cast<float4*>(&out[idx]) = r;
}

extern "C" void kernel_launch(void* const* d_in, const int* in_sizes, int n_in,
                              void* d_out, int out_size, void* d_ws, size_t ws_size,
                              hipStream_t stream) {
  (void)in_sizes; (void)n_in; (void)out_size; (void)ws_size;
  const float* x = (const float*)d_in[0];
  const float* Wq = (const float*)d_in[1];
  const float* Wk = (const float*)d_in[2];
  const float* Wv = (const float*)d_in[3];
  const float* Wp = (const float*)d_in[4];
  const float* gamma = (const float*)d_in[5];
  const float* beta = (const float*)d_in[6];
  char* ws = (char*)d_ws;
  short* xT = (short*)(ws + OFF_XT);
  short* Qn = (short*)(ws + OFF_QN);
  short* Kn = (short*)(ws + OFF_KN);
  short* Vt = (short*)(ws + OFF_VT);
  float* CI = (float*)(ws + OFF_CI);
  short* Wqb = (short*)(ws + OFF_WQ);
  short* Wkb = (short*)(ws + OFF_WK);
  short* Wvb = (short*)(ws + OFF_WV);
  short* Wpb = (short*)(ws + OFF_WP);
  float* S1 = (float*)(ws + OFF_S1);
  float* S2 = (float*)(ws + OFF_S2);
  float* AB = (float*)(ws + OFF_AB);
  short* yT = xT;            // reuse xT region (dead after projections)
  float* out = (float*)d_out;
  float* H = out;            // H staged in d_out; bn_apply rewrites in place

  hipMemsetAsync(S1, 0, 2048, stream);  // zero S1+S2

  dim3 blk(256);
  pack_w_kernel<<<dim3(256, 4), blk, 0, stream>>>(Wq, Wk, Wv, Wp, Wqb, Wkb, Wvb, Wpb);
  transpose_x_kernel<<<dim3(32, 4, 16), blk, 0, stream>>>(x, xT);
  proj_kernel<true><<<dim3(32, 16, 1), blk, 0, stream>>>(xT, Wqb, Qn, 64);
  proj_kernel<true><<<dim3(32, 16, 1), blk, 0, stream>>>(xT, Wkb, Kn, 64);
  proj_kernel<false><<<dim3(32, 16, 4), blk, 0, stream>>>(xT, Wvb, Vt, 256);
  colstats_kernel<<<dim3(32, 16), blk, 0, stream>>>(Qn, Kn, CI);
  attn_fsa_kernel<<<dim3(32, 16), blk, 0, stream>>>(x, Qn, Kn, Vt, CI, yT);
  wp_kernel<<<dim3(32, 16, 4), blk, 0, stream>>>(yT, Wpb, H, S1, S2);
  bn_final_kernel<<<1, 256, 0, stream>>>(S1, S2, gamma, beta, AB);
  bn_apply_kernel<<<dim3(8192), blk, 0, stream>>>(H, x, AB, out);
}

// Round 4
// 622.734 us; speedup vs baseline: 1.6459x; 1.6199x over previous
//
#include <hip/hip_runtime.h>
#include <math.h>

#define B_ 16
#define C_ 256
#define N_ 2048
#define D_ 64

typedef __attribute__((ext_vector_type(8))) short bf8;  // 8 bf16 (4 VGPRs)
typedef __attribute__((ext_vector_type(4))) float f4;   // MFMA C/D

#define MFMA16(A, Bv, Cv) __builtin_amdgcn_mfma_f32_16x16x32_bf16(A, Bv, Cv, 0, 0, 0)

__device__ __forceinline__ short f2b(float f) {  // f32 -> bf16 RNE
  unsigned u = __float_as_uint(f);
  u = (u + 0x7fff + ((u >> 16) & 1)) >> 16;
  return (short)u;
}
__device__ __forceinline__ float b2f(short s) {
  return __uint_as_float(((unsigned)(unsigned short)s) << 16);
}

// ---------------- workspace layout (bytes), ~42 MB ----------------
static constexpr size_t OFF_XT = 0;                          // bf16 [B][N][C] 16 MB (later yT)
static constexpr size_t OFF_QN = (size_t)16 << 20;           // bf16 [B][N][64] 4 MB
static constexpr size_t OFF_KN = (size_t)20 << 20;           // bf16 [B][N][64] 4 MB
static constexpr size_t OFF_VT = (size_t)24 << 20;           // bf16 [B][C][N] 16 MB
static constexpr size_t OFF_CI = (size_t)40 << 20;           // f32 [B][N] 128 KB
static constexpr size_t OFF_WQ = OFF_CI + ((size_t)128 << 10);
static constexpr size_t OFF_WK = OFF_WQ + ((size_t)32 << 10);
static constexpr size_t OFF_WV = OFF_WK + ((size_t)32 << 10);
static constexpr size_t OFF_WP = OFF_WV + ((size_t)128 << 10);
static constexpr size_t OFF_S1 = OFF_WP + ((size_t)128 << 10);
static constexpr size_t OFF_S2 = OFF_S1 + 1024;
static constexpr size_t OFF_AB = OFF_S2 + 1024;
static constexpr size_t OFF_P1 = OFF_AB + 4096;              // f32 [512][256] 512 KB
static constexpr size_t OFF_P2 = OFF_P1 + ((size_t)512 << 10);

// ---------------- pack weights to bf16 ----------------
__global__ void pack_w_kernel(const float* __restrict__ q, const float* __restrict__ k,
                              const float* __restrict__ v, const float* __restrict__ p,
                              short* wq, short* wk, short* wv, short* wp) {
  int idx = blockIdx.x * 256 + threadIdx.x;
  int which = blockIdx.y;
  const float* s = which == 0 ? q : which == 1 ? k : which == 2 ? v : p;
  short* d = which == 0 ? wq : which == 1 ? wk : which == 2 ? wv : wp;
  int cnt = which < 2 ? 64 * 256 : 256 * 256;
  if (idx < cnt) d[idx] = f2b(s[idx]);
}

// ---------------- x [B][C][N] f32 -> xT [B][N][C] bf16 ----------------
__global__ __launch_bounds__(256) void transpose_x_kernel(const float* __restrict__ x,
                                                          short* __restrict__ xT) {
  __shared__ float t[64][65];
  const int b = blockIdx.z, c0 = blockIdx.y * 64, n0 = blockIdx.x * 64;
  const int tid = threadIdx.x;
  const float* xp = x + ((size_t)b * C_ + c0) * N_ + n0;
#pragma unroll
  for (int i = 0; i < 16; ++i) {
    int idx = tid + i * 256;
    int cl = idx >> 6, nl = idx & 63;
    t[cl][nl] = xp[(size_t)cl * N_ + nl];
  }
  __syncthreads();
  short* op = xT + ((size_t)b * N_ + n0) * C_ + c0;
#pragma unroll
  for (int i = 0; i < 8; ++i) {
    int idx = tid + i * 256;  // 2048 ushort2 pairs
    int nl = idx >> 5, cl2 = (idx & 31) * 2;
    ushort2 v;
    v.x = (unsigned short)f2b(t[cl2][nl]);
    v.y = (unsigned short)f2b(t[cl2 + 1][nl]);
    *(ushort2*)(op + (size_t)nl * C_ + cl2) = v;
  }
}

// ---------------- projection GEMM: out = W(OxC) . x[b]  (MFMA, no LDS) ----------------
// OUTT=true : out[b][n][O] (for Qn/Kn, O=64);  OUTT=false: out[b][o][N] (for Vt, O=256)
template <bool OUTT>
__global__ __launch_bounds__(256, 4) void proj_kernel(const short* __restrict__ xT,
                                                      const short* __restrict__ W,
                                                      short* __restrict__ out, const int O) {
  const int tid = threadIdx.x;
  const int wv = tid >> 6, lane = tid & 63;
  const int li = lane & 15, quad = lane >> 4;
  const int b = blockIdx.y, n0 = blockIdx.x * 64, o0 = blockIdx.z * 64;
  const int n = n0 + wv * 16 + li;
  const short* xrow = xT + ((size_t)b * N_ + n) * C_ + quad * 8;
  f4 acc[4] = {};
  for (int ks = 0; ks < 8; ++ks) {
    bf8 bfr = *(const bf8*)(xrow + ks * 32);
#pragma unroll
    for (int ot = 0; ot < 4; ++ot) {
      bf8 afr = *(const bf8*)(W + (size_t)(o0 + ot * 16 + li) * C_ + ks * 32 + quad * 8);
      acc[ot] = MFMA16(afr, bfr, acc[ot]);
    }
  }
  if (OUTT) {
#pragma unroll
    for (int ot = 0; ot < 4; ++ot) {
      short4 v = {f2b(acc[ot].x), f2b(acc[ot].y), f2b(acc[ot].z), f2b(acc[ot].w)};
      *(short4*)(out + ((size_t)b * N_ + n) * O + o0 + ot * 16 + quad * 4) = v;
    }
  } else {
#pragma unroll
    for (int ot = 0; ot < 4; ++ot) {
#pragma unroll
      for (int r = 0; r < 4; ++r) {
        out[((size_t)b * C_ + o0 + ot * 16 + quad * 4 + r) * N_ + n] = f2b(acc[ot][r]);
      }
    }
  }
}

// ---------------- pass 1: cinv[b][m] = 1 / sum_n exp(energy[n][m]) ----------------
__global__ __launch_bounds__(256, 4) void colstats_kernel(const short* __restrict__ Qn,
                                                          const short* __restrict__ Kn,
                                                          float* __restrict__ cinv) {
  const int tid = threadIdx.x;
  const int wv = tid >> 6, lane = tid & 63;
  const int li = lane & 15, quad = lane >> 4;
  const int b = blockIdx.y, m0 = blockIdx.x * 64;
  const short* krow = Kn + ((size_t)b * N_ + m0 + wv * 16 + li) * D_ + quad * 8;
  bf8 af0 = *(const bf8*)(krow);
  bf8 af1 = *(const bf8*)(krow + 32);
  const short* qbase = Qn + ((size_t)b * N_ + li) * D_ + quad * 8;
  float csum[4] = {0.f, 0.f, 0.f, 0.f};
#pragma unroll 4
  for (int ns = 0; ns < N_; ns += 16) {
    const short* qrow = qbase + (size_t)ns * D_;
    bf8 b0 = *(const bf8*)(qrow);
    bf8 b1 = *(const bf8*)(qrow + 32);
    f4 s = {};
    s = MFMA16(af0, b0, s);
    s = MFMA16(af1, b1, s);
    csum[0] += __expf(s.x);
    csum[1] += __expf(s.y);
    csum[2] += __expf(s.z);
    csum[3] += __expf(s.w);
  }
#pragma unroll
  for (int r = 0; r < 4; ++r) {
#pragma unroll
    for (int m = 1; m < 16; m <<= 1) csum[r] += __shfl_xor(csum[r], m);
  }
  if (li == 0) {
#pragma unroll
    for (int r = 0; r < 4; ++r)
      cinv[(size_t)b * N_ + m0 + wv * 16 + quad * 4 + r] = 1.f / csum[r];
  }
}

// ---------------- pass 2: attention + fsa + y = x - fsa (-> yT bf16) ----------------
__global__ __launch_bounds__(256, 2) void attn_fsa_kernel(
    const float* __restrict__ x, const short* __restrict__ Qn, const short* __restrict__ Kn,
    const short* __restrict__ Vt, const float* __restrict__ cinv, short* __restrict__ yT) {
  __shared__ short pT[64][72];
  const int tid = threadIdx.x;
  const int wv = tid >> 6, lane = tid & 63;
  const int li = lane & 15, quad = lane >> 4;
  const int b = blockIdx.y, n0 = blockIdx.x * 64;
  const int nl = wv * 16 + li;
  const int n = n0 + nl;
  const short* qrow = Qn + ((size_t)b * N_ + n) * D_ + quad * 8;
  bf8 q0 = *(const bf8*)(qrow);
  bf8 q1 = *(const bf8*)(qrow + 32);
  const float* civ = cinv + (size_t)b * N_;
  f4 acc[16] = {};
  float rsum = 0.f;
  for (int mc = 0; mc < N_; mc += 64) {
    __syncthreads();
#pragma unroll
    for (int mt = 0; mt < 4; ++mt) {
      const short* krow = Kn + ((size_t)b * N_ + mc + mt * 16 + li) * D_ + quad * 8;
      bf8 a0 = *(const bf8*)(krow);
      bf8 a1 = *(const bf8*)(krow + 32);
      f4 s = {};
      s = MFMA16(a0, q0, s);
      s = MFMA16(a1, q1, s);
      short4 pv;
#pragma unroll
      for (int r = 0; r < 4; ++r) {
        float p = __expf(s[r]) * civ[mc + mt * 16 + quad * 4 + r];
        short ph = f2b(p);
        ((short*)&pv)[r] = ph;
        rsum += b2f(ph);
      }
      *(short4*)&pT[nl][mt * 16 + quad * 4] = pv;
    }
    __syncthreads();
#pragma unroll
    for (int kf = 0; kf < 2; ++kf) {
      bf8 pb = *(const bf8*)&pT[nl][kf * 32 + quad * 8];
#pragma unroll
      for (int ot = 0; ot < 16; ++ot) {
        bf8 va = *(const bf8*)(Vt + ((size_t)b * C_ + ot * 16 + li) * N_ + mc + kf * 32 + quad * 8);
        acc[ot] = MFMA16(va, pb, acc[ot]);
      }
    }
  }
  rsum += __shfl_xor(rsum, 16);
  rsum += __shfl_xor(rsum, 32);
  const float rinv = 1.f / (1e-9f + rsum);
  short* yrow = yT + ((size_t)b * N_ + n) * C_;
#pragma unroll
  for (int ot = 0; ot < 16; ++ot) {
    short4 v;
#pragma unroll
    for (int r = 0; r < 4; ++r) {
      int o = ot * 16 + quad * 4 + r;
      float xv = x[((size_t)b * C_ + o) * N_ + n];
      ((short*)&v)[r] = f2b(xv - acc[ot][r] * rinv);
    }
    *(short4*)(yrow + ot * 16 + quad * 4) = v;
  }
}

// ---------------- h = Wp . y -> H (=d_out) f32 + per-block BN partials ----------------
// No contended atomics: partials P1/P2[g][256], g = b*32 + n-block (512 groups).
__global__ __launch_bounds__(256, 4) void wp_kernel(const short* __restrict__ yT,
                                                    const short* __restrict__ Wp,
                                                    float* __restrict__ H,
                                                    float* __restrict__ P1,
                                                    float* __restrict__ P2) {
  __shared__ alignas(16) float ha[64][68];
  __shared__ float red1[64][4];
  __shared__ float red2[64][4];
  const int tid = threadIdx.x;
  const int wv = tid >> 6, lane = tid & 63;
  const int li = lane & 15, quad = lane >> 4;
  const int b = blockIdx.y, n0 = blockIdx.x * 64, o0 = blockIdx.z * 64;
  const int n = n0 + wv * 16 + li;
  const short* yrow = yT + ((size_t)b * N_ + n) * C_ + quad * 8;
  f4 acc[4] = {};
  for (int ks = 0; ks < 8; ++ks) {
    bf8 bfr = *(const bf8*)(yrow + ks * 32);
#pragma unroll
    for (int ot = 0; ot < 4; ++ot) {
      bf8 afr = *(const bf8*)(Wp + (size_t)(o0 + ot * 16 + li) * C_ + ks * 32 + quad * 8);
      acc[ot] = MFMA16(afr, bfr, acc[ot]);
    }
  }
  // stage 64o x 64n f32 tile to LDS (2-way bank alias only = free)
#pragma unroll
  for (int ot = 0; ot < 4; ++ot)
#pragma unroll
    for (int r = 0; r < 4; ++r) ha[ot * 16 + quad * 4 + r][wv * 16 + li] = acc[ot][r];
  __syncthreads();
  // vectorized H store + per-thread channel partial
  const int o = tid >> 2, nq = tid & 3;
  float s1p = 0.f, s2p = 0.f;
  float* hrow = H + ((size_t)b * C_ + o0 + o) * N_ + n0 + nq * 16;
#pragma unroll
  for (int j4 = 0; j4 < 4; ++j4) {
    float4 v = *reinterpret_cast<const float4*>(&ha[o][nq * 16 + j4 * 4]);
    s1p += v.x + v.y + v.z + v.w;
    s2p += v.x * v.x + v.y * v.y + v.z * v.z + v.w * v.w;
    reinterpret_cast<float4*>(hrow)[j4] = v;
  }
  red1[o][nq] = s1p;
  red2[o][nq] = s2p;
  __syncthreads();
  if (tid < 64) {
    float a1 = red1[tid][0] + red1[tid][1] + red1[tid][2] + red1[tid][3];
    float a2 = red2[tid][0] + red2[tid][1] + red2[tid][2] + red2[tid][3];
    const int g = b * 32 + blockIdx.x;
    P1[(size_t)g * 256 + o0 + tid] = a1;
    P2[(size_t)g * 256 + o0 + tid] = a2;
  }
}

// ---------------- fold partials (32 blocks; 32 light atomics/channel) ----------------
__global__ __launch_bounds__(256) void bn_reduce_kernel(const float* __restrict__ P1,
                                                        const float* __restrict__ P2,
                                                        float* __restrict__ S1,
                                                        float* __restrict__ S2) {
  const int c = threadIdx.x;
  float a1 = 0.f, a2 = 0.f;
#pragma unroll
  for (int k = 0; k < 16; ++k) {
    int g = blockIdx.x * 16 + k;
    a1 += P1[(size_t)g * 256 + c];
    a2 += P2[(size_t)g * 256 + c];
  }
  atomicAdd(&S1[c], a1);
  atomicAdd(&S2[c], a2);
}

// ---------------- BN finalize + fused epilogue ----------------
__global__ void bn_final_kernel(const float* __restrict__ s1, const float* __restrict__ s2,
                                const float* __restrict__ gamma, const float* __restrict__ beta,
                                float* __restrict__ AB) {
  int o = threadIdx.x;
  const float invn = 1.f / ((float)B_ * N_);
  float mean = s1[o] * invn;
  float var = s2[o] * invn - mean * mean;
  float inv = rsqrtf(var + 1e-5f);
  float A = gamma[o] * inv;
  AB[o] = A;
  AB[256 + o] = beta[o] - mean * A;
}

__global__ __launch_bounds__(256) void bn_apply_kernel(const float* __restrict__ H,
                                                       const float* __restrict__ x,
                                                       const float* __restrict__ AB,
                                                       float* __restrict__ out) {
  size_t idx = ((size_t)blockIdx.x * 256 + threadIdx.x) * 4;
  int o = (int)((idx >> 11) & 255);
  float a = AB[o], c = AB[256 + o];
  float4 h = *reinterpret_cast<const float4*>(&H[idx]);
  float4 xv = *reinterpret_cast<const float4*>(&x[idx]);
  float4 r;
  r.x = fmaxf(h.x * a + c, 0.f) + xv.x;
  r.y = fmaxf(h.y * a + c, 0.f) + xv.y;
  r.z = fmaxf(h.z * a + c, 0.f) + xv.z;
  r.w = fmaxf(h.w * a + c, 0.f) + xv.w;
  *reinterpret_cast<float4*>(&out[idx]) = r;
}

extern "C" void kernel_launch(void* const* d_in, const int* in_sizes, int n_in,
                              void* d_out, int out_size, void* d_ws, size_t ws_size,
                              hipStream_t stream) {
  (void)in_sizes; (void)n_in; (void)out_size; (void)ws_size;
  const float* x = (const float*)d_in[0];
  const float* Wq = (const float*)d_in[1];
  const float* Wk = (const float*)d_in[2];
  const float* Wv = (const float*)d_in[3];
  const float* Wp = (const float*)d_in[4];
  const float* gamma = (const float*)d_in[5];
  const float* beta = (const float*)d_in[6];
  char* ws = (char*)d_ws;
  short* xT = (short*)(ws + OFF_XT);
  short* Qn = (short*)(ws + OFF_QN);
  short* Kn = (short*)(ws + OFF_KN);
  short* Vt = (short*)(ws + OFF_VT);
  float* CI = (float*)(ws + OFF_CI);
  short* Wqb = (short*)(ws + OFF_WQ);
  short* Wkb = (short*)(ws + OFF_WK);
  short* Wvb = (short*)(ws + OFF_WV);
  short* Wpb = (short*)(ws + OFF_WP);
  float* S1 = (float*)(ws + OFF_S1);
  float* S2 = (float*)(ws + OFF_S2);
  float* AB = (float*)(ws + OFF_AB);
  float* P1 = (float*)(ws + OFF_P1);
  float* P2 = (float*)(ws + OFF_P2);
  short* yT = xT;            // reuse xT region (dead after projections)
  float* out = (float*)d_out;
  float* H = out;            // H staged in d_out; bn_apply rewrites in place

  hipMemsetAsync(S1, 0, 2048, stream);  // zero S1+S2

  dim3 blk(256);
  pack_w_kernel<<<dim3(256, 4), blk, 0, stream>>>(Wq, Wk, Wv, Wp, Wqb, Wkb, Wvb, Wpb);
  transpose_x_kernel<<<dim3(32, 4, 16), blk, 0, stream>>>(x, xT);
  proj_kernel<true><<<dim3(32, 16, 1), blk, 0, stream>>>(xT, Wqb, Qn, 64);
  proj_kernel<true><<<dim3(32, 16, 1), blk, 0, stream>>>(xT, Wkb, Kn, 64);
  proj_kernel<false><<<dim3(32, 16, 4), blk, 0, stream>>>(xT, Wvb, Vt, 256);
  colstats_kernel<<<dim3(32, 16), blk, 0, stream>>>(Qn, Kn, CI);
  attn_fsa_kernel<<<dim3(32, 16), blk, 0, stream>>>(x, Qn, Kn, Vt, CI, yT);
  wp_kernel<<<dim3(32, 16, 4), blk, 0, stream>>>(yT, Wpb, H, P1, P2);
  bn_reduce_kernel<<<dim3(32), blk, 0, stream>>>(P1, P2, S1, S2);
  bn_final_kernel<<<1, 256, 0, stream>>>(S1, S2, gamma, beta, AB);
  bn_apply_kernel<<<dim3(8192), blk, 0, stream>>>(H, x, AB, out);
}

// Round 5
// 603.760 us; speedup vs baseline: 1.6976x; 1.0314x over previous
//
#include <hip/hip_runtime.h>
#include <math.h>

#define B_ 16
#define C_ 256
#define N_ 2048
#define D_ 64

typedef __attribute__((ext_vector_type(8))) short bf8;  // 8 bf16 (4 VGPRs)
typedef __attribute__((ext_vector_type(4))) float f4;   // MFMA C/D

#define MFMA16(A, Bv, Cv) __builtin_amdgcn_mfma_f32_16x16x32_bf16(A, Bv, Cv, 0, 0, 0)

__device__ __forceinline__ short f2b(float f) {  // f32 -> bf16 RNE
  unsigned u = __float_as_uint(f);
  u = (u + 0x7fff + ((u >> 16) & 1)) >> 16;
  return (short)u;
}
__device__ __forceinline__ float b2f(short s) {
  return __uint_as_float(((unsigned)(unsigned short)s) << 16);
}

// ---------------- workspace layout (bytes), ~42 MB ----------------
static constexpr size_t OFF_XT = 0;                          // bf16 [B][N][C] 16 MB (later yT)
static constexpr size_t OFF_QN = (size_t)16 << 20;           // bf16 [B][N][64] 4 MB
static constexpr size_t OFF_KN = (size_t)20 << 20;           // bf16 [B][N][64] 4 MB
static constexpr size_t OFF_VT = (size_t)24 << 20;           // bf16 [B][C][N] 16 MB
static constexpr size_t OFF_CI = (size_t)40 << 20;           // f32 [B][N] 128 KB
static constexpr size_t OFF_WQ = OFF_CI + ((size_t)128 << 10);
static constexpr size_t OFF_WK = OFF_WQ + ((size_t)32 << 10);
static constexpr size_t OFF_WV = OFF_WK + ((size_t)32 << 10);
static constexpr size_t OFF_WP = OFF_WV + ((size_t)128 << 10);
static constexpr size_t OFF_S1 = OFF_WP + ((size_t)128 << 10);
static constexpr size_t OFF_S2 = OFF_S1 + 1024;
static constexpr size_t OFF_AB = OFF_S2 + 1024;
static constexpr size_t OFF_P1 = OFF_AB + 4096;              // f32 [512][256] 512 KB
static constexpr size_t OFF_P2 = OFF_P1 + ((size_t)512 << 10);

// ---------------- pack weights to bf16 ----------------
__global__ void pack_w_kernel(const float* __restrict__ q, const float* __restrict__ k,
                              const float* __restrict__ v, const float* __restrict__ p,
                              short* wq, short* wk, short* wv, short* wp) {
  int idx = blockIdx.x * 256 + threadIdx.x;
  int which = blockIdx.y;
  const float* s = which == 0 ? q : which == 1 ? k : which == 2 ? v : p;
  short* d = which == 0 ? wq : which == 1 ? wk : which == 2 ? wv : wp;
  int cnt = which < 2 ? 64 * 256 : 256 * 256;
  if (idx < cnt) d[idx] = f2b(s[idx]);
}

// ---------------- x [B][C][N] f32 -> xT [B][N][C] bf16 ----------------
__global__ __launch_bounds__(256) void transpose_x_kernel(const float* __restrict__ x,
                                                          short* __restrict__ xT) {
  __shared__ float t[64][65];
  const int b = blockIdx.z, c0 = blockIdx.y * 64, n0 = blockIdx.x * 64;
  const int tid = threadIdx.x;
  const float* xp = x + ((size_t)b * C_ + c0) * N_ + n0;
#pragma unroll
  for (int i = 0; i < 16; ++i) {
    int idx = tid + i * 256;
    int cl = idx >> 6, nl = idx & 63;
    t[cl][nl] = xp[(size_t)cl * N_ + nl];
  }
  __syncthreads();
  short* op = xT + ((size_t)b * N_ + n0) * C_ + c0;
#pragma unroll
  for (int i = 0; i < 8; ++i) {
    int idx = tid + i * 256;  // 2048 ushort2 pairs
    int nl = idx >> 5, cl2 = (idx & 31) * 2;
    ushort2 v;
    v.x = (unsigned short)f2b(t[cl2][nl]);
    v.y = (unsigned short)f2b(t[cl2 + 1][nl]);
    *(ushort2*)(op + (size_t)nl * C_ + cl2) = v;
  }
}

// ---------------- projection GEMM: out = W(OxC) . x[b]  (MFMA, no LDS) ----------------
template <bool OUTT>
__global__ __launch_bounds__(256, 4) void proj_kernel(const short* __restrict__ xT,
                                                      const short* __restrict__ W,
                                                      short* __restrict__ out, const int O) {
  const int tid = threadIdx.x;
  const int wv = tid >> 6, lane = tid & 63;
  const int li = lane & 15, quad = lane >> 4;
  const int b = blockIdx.y, n0 = blockIdx.x * 64, o0 = blockIdx.z * 64;
  const int n = n0 + wv * 16 + li;
  const short* xrow = xT + ((size_t)b * N_ + n) * C_ + quad * 8;
  f4 acc[4] = {};
  for (int ks = 0; ks < 8; ++ks) {
    bf8 bfr = *(const bf8*)(xrow + ks * 32);
#pragma unroll
    for (int ot = 0; ot < 4; ++ot) {
      bf8 afr = *(const bf8*)(W + (size_t)(o0 + ot * 16 + li) * C_ + ks * 32 + quad * 8);
      acc[ot] = MFMA16(afr, bfr, acc[ot]);
    }
  }
  if (OUTT) {
#pragma unroll
    for (int ot = 0; ot < 4; ++ot) {
      short4 v = {f2b(acc[ot].x), f2b(acc[ot].y), f2b(acc[ot].z), f2b(acc[ot].w)};
      *(short4*)(out + ((size_t)b * N_ + n) * O + o0 + ot * 16 + quad * 4) = v;
    }
  } else {
#pragma unroll
    for (int ot = 0; ot < 4; ++ot) {
#pragma unroll
      for (int r = 0; r < 4; ++r) {
        out[((size_t)b * C_ + o0 + ot * 16 + quad * 4 + r) * N_ + n] = f2b(acc[ot][r]);
      }
    }
  }
}

// ---------------- pass 1: cinv[b][m] = 1 / sum_n exp(energy[n][m]) ----------------
__global__ __launch_bounds__(256, 4) void colstats_kernel(const short* __restrict__ Qn,
                                                          const short* __restrict__ Kn,
                                                          float* __restrict__ cinv) {
  const int tid = threadIdx.x;
  const int wv = tid >> 6, lane = tid & 63;
  const int li = lane & 15, quad = lane >> 4;
  const int b = blockIdx.y, m0 = blockIdx.x * 64;
  const short* krow = Kn + ((size_t)b * N_ + m0 + wv * 16 + li) * D_ + quad * 8;
  bf8 af0 = *(const bf8*)(krow);
  bf8 af1 = *(const bf8*)(krow + 32);
  const short* qbase = Qn + ((size_t)b * N_ + li) * D_ + quad * 8;
  float csum[4] = {0.f, 0.f, 0.f, 0.f};
#pragma unroll 4
  for (int ns = 0; ns < N_; ns += 16) {
    const short* qrow = qbase + (size_t)ns * D_;
    bf8 b0 = *(const bf8*)(qrow);
    bf8 b1 = *(const bf8*)(qrow + 32);
    f4 s = {};
    s = MFMA16(af0, b0, s);
    s = MFMA16(af1, b1, s);
    csum[0] += __expf(s.x);
    csum[1] += __expf(s.y);
    csum[2] += __expf(s.z);
    csum[3] += __expf(s.w);
  }
#pragma unroll
  for (int r = 0; r < 4; ++r) {
#pragma unroll
    for (int m = 1; m < 16; m <<= 1) csum[r] += __shfl_xor(csum[r], m);
  }
  if (li == 0) {
#pragma unroll
    for (int r = 0; r < 4; ++r)
      cinv[(size_t)b * N_ + m0 + wv * 16 + quad * 4 + r] = 1.f / csum[r];
  }
}

// ---------------- pass 2: attention + fsa + y = x - fsa (-> yT bf16) ----------------
// Barrier-free: each wave owns a private double-buffered LDS slab for its P tile.
// Writer lane (li,quad) holds P[m=mt*16+quad*4+r][n=li]; reader lane (li,quad)
// needs P[n=li][m=kf*32+quad*8..+7] -- same li, so producer==consumer wave.
__global__ __launch_bounds__(256, 2) void attn_fsa_kernel(
    const float* __restrict__ x, const short* __restrict__ Qn, const short* __restrict__ Kn,
    const short* __restrict__ Vt, const float* __restrict__ cinv, short* __restrict__ yT) {
  __shared__ short pT[4][2][16][72];  // [wave][dbuf][n=li][m], pitch 72 (144B, 16B-mult)
  const int tid = threadIdx.x;
  const int wv = tid >> 6, lane = tid & 63;
  const int li = lane & 15, quad = lane >> 4;
  const int b = blockIdx.y, n0 = blockIdx.x * 64;
  const int nl = wv * 16 + li;
  const int n = n0 + nl;
  const short* qrow = Qn + ((size_t)b * N_ + n) * D_ + quad * 8;
  bf8 q0 = *(const bf8*)(qrow);       // loop-invariant Q B-frags
  bf8 q1 = *(const bf8*)(qrow + 32);
  const float* civ = cinv + (size_t)b * N_;
  f4 acc[16] = {};
  float rsum = 0.f;
  int dbuf = 0;
  for (int mc = 0; mc < N_; mc += 64) {
    short* myP = &pT[wv][dbuf][0][0];
    dbuf ^= 1;
#pragma unroll
    for (int mt = 0; mt < 4; ++mt) {
      const short* krow = Kn + ((size_t)b * N_ + mc + mt * 16 + li) * D_ + quad * 8;
      bf8 a0 = *(const bf8*)(krow);
      bf8 a1 = *(const bf8*)(krow + 32);
      f4 s = {};
      s = MFMA16(a0, q0, s);
      s = MFMA16(a1, q1, s);
      short4 pv;
#pragma unroll
      for (int r = 0; r < 4; ++r) {
        float p = __expf(s[r]) * civ[mc + mt * 16 + quad * 4 + r];
        short ph = f2b(p);
        ((short*)&pv)[r] = ph;
        rsum += b2f(ph);  // bf16-rounded value for num/denom consistency
      }
      *(short4*)(myP + li * 72 + mt * 16 + quad * 4) = pv;
    }
#pragma unroll
    for (int kf = 0; kf < 2; ++kf) {
      bf8 pb = *(const bf8*)(myP + li * 72 + kf * 32 + quad * 8);
#pragma unroll
      for (int ot = 0; ot < 16; ++ot) {
        bf8 va = *(const bf8*)(Vt + ((size_t)b * C_ + ot * 16 + li) * N_ + mc + kf * 32 + quad * 8);
        acc[ot] = MFMA16(va, pb, acc[ot]);
      }
    }
  }
  rsum += __shfl_xor(rsum, 16);
  rsum += __shfl_xor(rsum, 32);
  const float rinv = 1.f / (1e-9f + rsum);
  short* yrow = yT + ((size_t)b * N_ + n) * C_;
#pragma unroll
  for (int ot = 0; ot < 16; ++ot) {
    short4 v;
#pragma unroll
    for (int r = 0; r < 4; ++r) {
      int o = ot * 16 + quad * 4 + r;
      float xv = x[((size_t)b * C_ + o) * N_ + n];
      ((short*)&v)[r] = f2b(xv - acc[ot][r] * rinv);
    }
    *(short4*)(yrow + ot * 16 + quad * 4) = v;
  }
}

// ---------------- h = Wp . y -> H (=d_out) f32 + per-block BN partials ----------------
__global__ __launch_bounds__(256, 4) void wp_kernel(const short* __restrict__ yT,
                                                    const short* __restrict__ Wp,
                                                    float* __restrict__ H,
                                                    float* __restrict__ P1,
                                                    float* __restrict__ P2) {
  __shared__ alignas(16) float ha[64][68];
  __shared__ float red1[64][4];
  __shared__ float red2[64][4];
  const int tid = threadIdx.x;
  const int wv = tid >> 6, lane = tid & 63;
  const int li = lane & 15, quad = lane >> 4;
  const int b = blockIdx.y, n0 = blockIdx.x * 64, o0 = blockIdx.z * 64;
  const int n = n0 + wv * 16 + li;
  const short* yrow = yT + ((size_t)b * N_ + n) * C_ + quad * 8;
  f4 acc[4] = {};
  for (int ks = 0; ks < 8; ++ks) {
    bf8 bfr = *(const bf8*)(yrow + ks * 32);
#pragma unroll
    for (int ot = 0; ot < 4; ++ot) {
      bf8 afr = *(const bf8*)(Wp + (size_t)(o0 + ot * 16 + li) * C_ + ks * 32 + quad * 8);
      acc[ot] = MFMA16(afr, bfr, acc[ot]);
    }
  }
#pragma unroll
  for (int ot = 0; ot < 4; ++ot)
#pragma unroll
    for (int r = 0; r < 4; ++r) ha[ot * 16 + quad * 4 + r][wv * 16 + li] = acc[ot][r];
  __syncthreads();
  const int o = tid >> 2, nq = tid & 3;
  float s1p = 0.f, s2p = 0.f;
  float* hrow = H + ((size_t)b * C_ + o0 + o) * N_ + n0 + nq * 16;
#pragma unroll
  for (int j4 = 0; j4 < 4; ++j4) {
    float4 v = *reinterpret_cast<const float4*>(&ha[o][nq * 16 + j4 * 4]);
    s1p += v.x + v.y + v.z + v.w;
    s2p += v.x * v.x + v.y * v.y + v.z * v.z + v.w * v.w;
    reinterpret_cast<float4*>(hrow)[j4] = v;
  }
  red1[o][nq] = s1p;
  red2[o][nq] = s2p;
  __syncthreads();
  if (tid < 64) {
    float a1 = red1[tid][0] + red1[tid][1] + red1[tid][2] + red1[tid][3];
    float a2 = red2[tid][0] + red2[tid][1] + red2[tid][2] + red2[tid][3];
    const int g = b * 32 + blockIdx.x;
    P1[(size_t)g * 256 + o0 + tid] = a1;
    P2[(size_t)g * 256 + o0 + tid] = a2;
  }
}

// ---------------- fold partials (32 blocks; 32 light atomics/channel) ----------------
__global__ __launch_bounds__(256) void bn_reduce_kernel(const float* __restrict__ P1,
                                                        const float* __restrict__ P2,
                                                        float* __restrict__ S1,
                                                        float* __restrict__ S2) {
  const int c = threadIdx.x;
  float a1 = 0.f, a2 = 0.f;
#pragma unroll
  for (int k = 0; k < 16; ++k) {
    int g = blockIdx.x * 16 + k;
    a1 += P1[(size_t)g * 256 + c];
    a2 += P2[(size_t)g * 256 + c];
  }
  atomicAdd(&S1[c], a1);
  atomicAdd(&S2[c], a2);
}

// ---------------- BN finalize + fused epilogue ----------------
__global__ void bn_final_kernel(const float* __restrict__ s1, const float* __restrict__ s2,
                                const float* __restrict__ gamma, const float* __restrict__ beta,
                                float* __restrict__ AB) {
  int o = threadIdx.x;
  const float invn = 1.f / ((float)B_ * N_);
  float mean = s1[o] * invn;
  float var = s2[o] * invn - mean * mean;
  float inv = rsqrtf(var + 1e-5f);
  float A = gamma[o] * inv;
  AB[o] = A;
  AB[256 + o] = beta[o] - mean * A;
}

__global__ __launch_bounds__(256) void bn_apply_kernel(const float* __restrict__ H,
                                                       const float* __restrict__ x,
                                                       const float* __restrict__ AB,
                                                       float* __restrict__ out) {
  size_t idx = ((size_t)blockIdx.x * 256 + threadIdx.x) * 4;
  int o = (int)((idx >> 11) & 255);
  float a = AB[o], c = AB[256 + o];
  float4 h = *reinterpret_cast<const float4*>(&H[idx]);
  float4 xv = *reinterpret_cast<const float4*>(&x[idx]);
  float4 r;
  r.x = fmaxf(h.x * a + c, 0.f) + xv.x;
  r.y = fmaxf(h.y * a + c, 0.f) + xv.y;
  r.z = fmaxf(h.z * a + c, 0.f) + xv.z;
  r.w = fmaxf(h.w * a + c, 0.f) + xv.w;
  *reinterpret_cast<float4*>(&out[idx]) = r;
}

extern "C" void kernel_launch(void* const* d_in, const int* in_sizes, int n_in,
                              void* d_out, int out_size, void* d_ws, size_t ws_size,
                              hipStream_t stream) {
  (void)in_sizes; (void)n_in; (void)out_size; (void)ws_size;
  const float* x = (const float*)d_in[0];
  const float* Wq = (const float*)d_in[1];
  const float* Wk = (const float*)d_in[2];
  const float* Wv = (const float*)d_in[3];
  const float* Wp = (const float*)d_in[4];
  const float* gamma = (const float*)d_in[5];
  const float* beta = (const float*)d_in[6];
  char* ws = (char*)d_ws;
  short* xT = (short*)(ws + OFF_XT);
  short* Qn = (short*)(ws + OFF_QN);
  short* Kn = (short*)(ws + OFF_KN);
  short* Vt = (short*)(ws + OFF_VT);
  float* CI = (float*)(ws + OFF_CI);
  short* Wqb = (short*)(ws + OFF_WQ);
  short* Wkb = (short*)(ws + OFF_WK);
  short* Wvb = (short*)(ws + OFF_WV);
  short* Wpb = (short*)(ws + OFF_WP);
  float* S1 = (float*)(ws + OFF_S1);
  float* S2 = (float*)(ws + OFF_S2);
  float* AB = (float*)(ws + OFF_AB);
  float* P1 = (float*)(ws + OFF_P1);
  float* P2 = (float*)(ws + OFF_P2);
  short* yT = xT;            // reuse xT region (dead after projections)
  float* out = (float*)d_out;
  float* H = out;            // H staged in d_out; bn_apply rewrites in place

  hipMemsetAsync(S1, 0, 2048, stream);  // zero S1+S2

  dim3 blk(256);
  pack_w_kernel<<<dim3(256, 4), blk, 0, stream>>>(Wq, Wk, Wv, Wp, Wqb, Wkb, Wvb, Wpb);
  transpose_x_kernel<<<dim3(32, 4, 16), blk, 0, stream>>>(x, xT);
  proj_kernel<true><<<dim3(32, 16, 1), blk, 0, stream>>>(xT, Wqb, Qn, 64);
  proj_kernel<true><<<dim3(32, 16, 1), blk, 0, stream>>>(xT, Wkb, Kn, 64);
  proj_kernel<false><<<dim3(32, 16, 4), blk, 0, stream>>>(xT, Wvb, Vt, 256);
  colstats_kernel<<<dim3(32, 16), blk, 0, stream>>>(Qn, Kn, CI);
  attn_fsa_kernel<<<dim3(32, 16), blk, 0, stream>>>(x, Qn, Kn, Vt, CI, yT);
  wp_kernel<<<dim3(32, 16, 4), blk, 0, stream>>>(yT, Wpb, H, P1, P2);
  bn_reduce_kernel<<<dim3(32), blk, 0, stream>>>(P1, P2, S1, S2);
  bn_final_kernel<<<1, 256, 0, stream>>>(S1, S2, gamma, beta, AB);
  bn_apply_kernel<<<dim3(8192), blk, 0, stream>>>(H, x, AB, out);
}

// Round 6
// 405.281 us; speedup vs baseline: 2.5289x; 1.4897x over previous
//
#include <hip/hip_runtime.h>
#include <math.h>

#define B_ 16
#define C_ 256
#define N_ 2048
#define D_ 64

typedef __attribute__((ext_vector_type(8))) short bf8;  // 8 bf16 (4 VGPRs)
typedef __attribute__((ext_vector_type(4))) float f4;   // MFMA C/D

#define MFMA16(A, Bv, Cv) __builtin_amdgcn_mfma_f32_16x16x32_bf16(A, Bv, Cv, 0, 0, 0)

__device__ __forceinline__ short f2b(float f) {  // f32 -> bf16 RNE
  unsigned u = __float_as_uint(f);
  u = (u + 0x7fff + ((u >> 16) & 1)) >> 16;
  return (short)u;
}
__device__ __forceinline__ float b2f(short s) {
  return __uint_as_float(((unsigned)(unsigned short)s) << 16);
}

// ---------------- workspace layout (bytes), ~42 MB ----------------
static constexpr size_t OFF_XT = 0;                          // bf16 [B][N][C] 16 MB (later yT)
static constexpr size_t OFF_QN = (size_t)16 << 20;           // bf16 [B][N][64] 4 MB
static constexpr size_t OFF_KN = (size_t)20 << 20;           // bf16 [B][N][64] 4 MB
static constexpr size_t OFF_VT = (size_t)24 << 20;           // bf16 [B][C][N] 16 MB
static constexpr size_t OFF_CI = (size_t)40 << 20;           // f32 [B][N] 128 KB
static constexpr size_t OFF_WQ = OFF_CI + ((size_t)128 << 10);
static constexpr size_t OFF_WK = OFF_WQ + ((size_t)32 << 10);
static constexpr size_t OFF_WV = OFF_WK + ((size_t)32 << 10);
static constexpr size_t OFF_WP = OFF_WV + ((size_t)128 << 10);
static constexpr size_t OFF_S1 = OFF_WP + ((size_t)128 << 10);
static constexpr size_t OFF_S2 = OFF_S1 + 1024;
static constexpr size_t OFF_AB = OFF_S2 + 1024;
static constexpr size_t OFF_P1 = OFF_AB + 4096;              // f32 [512][256] 512 KB
static constexpr size_t OFF_P2 = OFF_P1 + ((size_t)512 << 10);

// ---------------- pack weights to bf16 ----------------
__global__ void pack_w_kernel(const float* __restrict__ q, const float* __restrict__ k,
                              const float* __restrict__ v, const float* __restrict__ p,
                              short* wq, short* wk, short* wv, short* wp) {
  int idx = blockIdx.x * 256 + threadIdx.x;
  int which = blockIdx.y;
  const float* s = which == 0 ? q : which == 1 ? k : which == 2 ? v : p;
  short* d = which == 0 ? wq : which == 1 ? wk : which == 2 ? wv : wp;
  int cnt = which < 2 ? 64 * 256 : 256 * 256;
  if (idx < cnt) d[idx] = f2b(s[idx]);
}

// ---------------- x [B][C][N] f32 -> xT [B][N][C] bf16 ----------------
__global__ __launch_bounds__(256) void transpose_x_kernel(const float* __restrict__ x,
                                                          short* __restrict__ xT) {
  __shared__ float t[64][65];
  const int b = blockIdx.z, c0 = blockIdx.y * 64, n0 = blockIdx.x * 64;
  const int tid = threadIdx.x;
  const float* xp = x + ((size_t)b * C_ + c0) * N_ + n0;
#pragma unroll
  for (int i = 0; i < 16; ++i) {
    int idx = tid + i * 256;
    int cl = idx >> 6, nl = idx & 63;
    t[cl][nl] = xp[(size_t)cl * N_ + nl];
  }
  __syncthreads();
  short* op = xT + ((size_t)b * N_ + n0) * C_ + c0;
#pragma unroll
  for (int i = 0; i < 8; ++i) {
    int idx = tid + i * 256;  // 2048 ushort2 pairs
    int nl = idx >> 5, cl2 = (idx & 31) * 2;
    ushort2 v;
    v.x = (unsigned short)f2b(t[cl2][nl]);
    v.y = (unsigned short)f2b(t[cl2 + 1][nl]);
    *(ushort2*)(op + (size_t)nl * C_ + cl2) = v;
  }
}

// ---------------- projection GEMM: out = W(OxC) . x[b]  (MFMA, no LDS) ----------------
template <bool OUTT>
__global__ __launch_bounds__(256, 4) void proj_kernel(const short* __restrict__ xT,
                                                      const short* __restrict__ W,
                                                      short* __restrict__ out, const int O) {
  const int tid = threadIdx.x;
  const int wv = tid >> 6, lane = tid & 63;
  const int li = lane & 15, quad = lane >> 4;
  const int b = blockIdx.y, n0 = blockIdx.x * 64, o0 = blockIdx.z * 64;
  const int n = n0 + wv * 16 + li;
  const short* xrow = xT + ((size_t)b * N_ + n) * C_ + quad * 8;
  f4 acc[4] = {};
  for (int ks = 0; ks < 8; ++ks) {
    bf8 bfr = *(const bf8*)(xrow + ks * 32);
#pragma unroll
    for (int ot = 0; ot < 4; ++ot) {
      bf8 afr = *(const bf8*)(W + (size_t)(o0 + ot * 16 + li) * C_ + ks * 32 + quad * 8);
      acc[ot] = MFMA16(afr, bfr, acc[ot]);
    }
  }
  if (OUTT) {
#pragma unroll
    for (int ot = 0; ot < 4; ++ot) {
      short4 v = {f2b(acc[ot].x), f2b(acc[ot].y), f2b(acc[ot].z), f2b(acc[ot].w)};
      *(short4*)(out + ((size_t)b * N_ + n) * O + o0 + ot * 16 + quad * 4) = v;
    }
  } else {
#pragma unroll
    for (int ot = 0; ot < 4; ++ot) {
#pragma unroll
      for (int r = 0; r < 4; ++r) {
        out[((size_t)b * C_ + o0 + ot * 16 + quad * 4 + r) * N_ + n] = f2b(acc[ot][r]);
      }
    }
  }
}

// ---------------- pass 1: cinv[b][m] = 1 / sum_n exp(energy[n][m]) ----------------
__global__ __launch_bounds__(256, 4) void colstats_kernel(const short* __restrict__ Qn,
                                                          const short* __restrict__ Kn,
                                                          float* __restrict__ cinv) {
  const int tid = threadIdx.x;
  const int wv = tid >> 6, lane = tid & 63;
  const int li = lane & 15, quad = lane >> 4;
  const int b = blockIdx.y, m0 = blockIdx.x * 64;
  const short* krow = Kn + ((size_t)b * N_ + m0 + wv * 16 + li) * D_ + quad * 8;
  bf8 af0 = *(const bf8*)(krow);
  bf8 af1 = *(const bf8*)(krow + 32);
  const short* qbase = Qn + ((size_t)b * N_ + li) * D_ + quad * 8;
  float csum[4] = {0.f, 0.f, 0.f, 0.f};
#pragma unroll 4
  for (int ns = 0; ns < N_; ns += 16) {
    const short* qrow = qbase + (size_t)ns * D_;
    bf8 b0 = *(const bf8*)(qrow);
    bf8 b1 = *(const bf8*)(qrow + 32);
    f4 s = {};
    s = MFMA16(af0, b0, s);
    s = MFMA16(af1, b1, s);
    csum[0] += __expf(s.x);
    csum[1] += __expf(s.y);
    csum[2] += __expf(s.z);
    csum[3] += __expf(s.w);
  }
#pragma unroll
  for (int r = 0; r < 4; ++r) {
#pragma unroll
    for (int m = 1; m < 16; m <<= 1) csum[r] += __shfl_xor(csum[r], m);
  }
  if (li == 0) {
#pragma unroll
    for (int r = 0; r < 4; ++r)
      cinv[(size_t)b * N_ + m0 + wv * 16 + quad * 4 + r] = 1.f / csum[r];
  }
}

// ---------------- pass 2: attention + fsa + y = x - fsa (-> yT bf16) ----------------
// o-split PV: S-phase waves own 16-n stripes (as before); PV waves own 64-o
// ranges, so each wave loads only 8 V frags/chunk (all in flight, reused 4x
// across n-tiles in registers). pT double-buffered, ONE barrier per chunk:
// S(t+2) writes buf only after barrier(t+1), which proves all PV(t) reads done.
__global__ __launch_bounds__(256, 2) void attn_fsa_kernel(
    const float* __restrict__ x, const short* __restrict__ Qn, const short* __restrict__ Kn,
    const short* __restrict__ Vt, const float* __restrict__ cinv, short* __restrict__ yT) {
  __shared__ short pT[2][64][72];  // [dbuf][n][m], pitch 72 (144 B, 16B-mult)
  __shared__ float racc[64];
  const int tid = threadIdx.x;
  const int wv = tid >> 6, lane = tid & 63;
  const int li = lane & 15, quad = lane >> 4;
  const int b = blockIdx.y, n0 = blockIdx.x * 64;
  const int ns = wv * 16 + li;  // n this lane produces in S phase
  const int n = n0 + ns;
  const int ob = wv * 64;       // o-range this wave owns in PV
  const short* qrow = Qn + ((size_t)b * N_ + n) * D_ + quad * 8;
  bf8 q0 = *(const bf8*)(qrow);  // loop-invariant Q B-frags
  bf8 q1 = *(const bf8*)(qrow + 32);
  const float* civ = cinv + (size_t)b * N_;
  f4 acc[4][4] = {};  // [ot][nt]: o = ob+ot*16+quad*4+r, n = n0+nt*16+li
  float rsum = 0.f;
  for (int it = 0; it < N_ / 64; ++it) {
    const int mc = it * 64;
    short* Pb = &pT[it & 1][0][0];
    // V frags for this chunk: 8 independent 16B loads, all issued up front
    bf8 va[4][2];
#pragma unroll
    for (int ot = 0; ot < 4; ++ot)
#pragma unroll
      for (int kf = 0; kf < 2; ++kf)
        va[ot][kf] = *(const bf8*)(Vt + ((size_t)b * C_ + ob + ot * 16 + li) * N_ +
                                   mc + kf * 32 + quad * 8);
    // S phase (n-stripe ownership)
#pragma unroll
    for (int mt = 0; mt < 4; ++mt) {
      const short* krow = Kn + ((size_t)b * N_ + mc + mt * 16 + li) * D_ + quad * 8;
      bf8 a0 = *(const bf8*)(krow);
      bf8 a1 = *(const bf8*)(krow + 32);
      f4 s = {};
      s = MFMA16(a0, q0, s);
      s = MFMA16(a1, q1, s);
      short4 pv;
#pragma unroll
      for (int r = 0; r < 4; ++r) {
        float p = __expf(s[r]) * civ[mc + mt * 16 + quad * 4 + r];
        short ph = f2b(p);
        ((short*)&pv)[r] = ph;
        rsum += b2f(ph);  // bf16-rounded value for num/denom consistency
      }
      *(short4*)(Pb + ns * 72 + mt * 16 + quad * 4) = pv;
    }
    __syncthreads();
    // PV phase (o-range ownership): va reused across 4 n-tiles
#pragma unroll
    for (int nt = 0; nt < 4; ++nt) {
#pragma unroll
      for (int kf = 0; kf < 2; ++kf) {
        bf8 pb = *(const bf8*)(Pb + (nt * 16 + li) * 72 + kf * 32 + quad * 8);
#pragma unroll
        for (int ot = 0; ot < 4; ++ot) acc[ot][nt] = MFMA16(va[ot][kf], pb, acc[ot][nt]);
      }
    }
  }
  rsum += __shfl_xor(rsum, 16);
  rsum += __shfl_xor(rsum, 32);
  if (quad == 0) racc[ns] = rsum;
  __syncthreads();
#pragma unroll
  for (int nt = 0; nt < 4; ++nt) {
    const int nn = n0 + nt * 16 + li;
    const float rinv = 1.f / (1e-9f + racc[nt * 16 + li]);
    short* yrow = yT + ((size_t)b * N_ + nn) * C_ + ob;
#pragma unroll
    for (int ot = 0; ot < 4; ++ot) {
      short4 v;
#pragma unroll
      for (int r = 0; r < 4; ++r) {
        int o = ob + ot * 16 + quad * 4 + r;
        float xv = x[((size_t)b * C_ + o) * N_ + nn];
        ((short*)&v)[r] = f2b(xv - acc[ot][nt][r] * rinv);
      }
      *(short4*)(yrow + ot * 16 + quad * 4) = v;
    }
  }
}

// ---------------- h = Wp . y -> H (=d_out) f32 + per-block BN partials ----------------
__global__ __launch_bounds__(256, 4) void wp_kernel(const short* __restrict__ yT,
                                                    const short* __restrict__ Wp,
                                                    float* __restrict__ H,
                                                    float* __restrict__ P1,
                                                    float* __restrict__ P2) {
  __shared__ alignas(16) float ha[64][68];
  __shared__ float red1[64][4];
  __shared__ float red2[64][4];
  const int tid = threadIdx.x;
  const int wv = tid >> 6, lane = tid & 63;
  const int li = lane & 15, quad = lane >> 4;
  const int b = blockIdx.y, n0 = blockIdx.x * 64, o0 = blockIdx.z * 64;
  const int n = n0 + wv * 16 + li;
  const short* yrow = yT + ((size_t)b * N_ + n) * C_ + quad * 8;
  f4 acc[4] = {};
  for (int ks = 0; ks < 8; ++ks) {
    bf8 bfr = *(const bf8*)(yrow + ks * 32);
#pragma unroll
    for (int ot = 0; ot < 4; ++ot) {
      bf8 afr = *(const bf8*)(Wp + (size_t)(o0 + ot * 16 + li) * C_ + ks * 32 + quad * 8);
      acc[ot] = MFMA16(afr, bfr, acc[ot]);
    }
  }
#pragma unroll
  for (int ot = 0; ot < 4; ++ot)
#pragma unroll
    for (int r = 0; r < 4; ++r) ha[ot * 16 + quad * 4 + r][wv * 16 + li] = acc[ot][r];
  __syncthreads();
  const int o = tid >> 2, nq = tid & 3;
  float s1p = 0.f, s2p = 0.f;
  float* hrow = H + ((size_t)b * C_ + o0 + o) * N_ + n0 + nq * 16;
#pragma unroll
  for (int j4 = 0; j4 < 4; ++j4) {
    float4 v = *reinterpret_cast<const float4*>(&ha[o][nq * 16 + j4 * 4]);
    s1p += v.x + v.y + v.z + v.w;
    s2p += v.x * v.x + v.y * v.y + v.z * v.z + v.w * v.w;
    reinterpret_cast<float4*>(hrow)[j4] = v;
  }
  red1[o][nq] = s1p;
  red2[o][nq] = s2p;
  __syncthreads();
  if (tid < 64) {
    float a1 = red1[tid][0] + red1[tid][1] + red1[tid][2] + red1[tid][3];
    float a2 = red2[tid][0] + red2[tid][1] + red2[tid][2] + red2[tid][3];
    const int g = b * 32 + blockIdx.x;
    P1[(size_t)g * 256 + o0 + tid] = a1;
    P2[(size_t)g * 256 + o0 + tid] = a2;
  }
}

// ---------------- fold partials (32 blocks; 32 light atomics/channel) ----------------
__global__ __launch_bounds__(256) void bn_reduce_kernel(const float* __restrict__ P1,
                                                        const float* __restrict__ P2,
                                                        float* __restrict__ S1,
                                                        float* __restrict__ S2) {
  const int c = threadIdx.x;
  float a1 = 0.f, a2 = 0.f;
#pragma unroll
  for (int k = 0; k < 16; ++k) {
    int g = blockIdx.x * 16 + k;
    a1 += P1[(size_t)g * 256 + c];
    a2 += P2[(size_t)g * 256 + c];
  }
  atomicAdd(&S1[c], a1);
  atomicAdd(&S2[c], a2);
}

// ---------------- BN finalize + fused epilogue ----------------
__global__ void bn_final_kernel(const float* __restrict__ s1, const float* __restrict__ s2,
                                const float* __restrict__ gamma, const float* __restrict__ beta,
                                float* __restrict__ AB) {
  int o = threadIdx.x;
  const float invn = 1.f / ((float)B_ * N_);
  float mean = s1[o] * invn;
  float var = s2[o] * invn - mean * mean;
  float inv = rsqrtf(var + 1e-5f);
  float A = gamma[o] * inv;
  AB[o] = A;
  AB[256 + o] = beta[o] - mean * A;
}

__global__ __launch_bounds__(256) void bn_apply_kernel(const float* __restrict__ H,
                                                       const float* __restrict__ x,
                                                       const float* __restrict__ AB,
                                                       float* __restrict__ out) {
  size_t idx = ((size_t)blockIdx.x * 256 + threadIdx.x) * 4;
  int o = (int)((idx >> 11) & 255);
  float a = AB[o], c = AB[256 + o];
  float4 h = *reinterpret_cast<const float4*>(&H[idx]);
  float4 xv = *reinterpret_cast<const float4*>(&x[idx]);
  float4 r;
  r.x = fmaxf(h.x * a + c, 0.f) + xv.x;
  r.y = fmaxf(h.y * a + c, 0.f) + xv.y;
  r.z = fmaxf(h.z * a + c, 0.f) + xv.z;
  r.w = fmaxf(h.w * a + c, 0.f) + xv.w;
  *reinterpret_cast<float4*>(&out[idx]) = r;
}

extern "C" void kernel_launch(void* const* d_in, const int* in_sizes, int n_in,
                              void* d_out, int out_size, void* d_ws, size_t ws_size,
                              hipStream_t stream) {
  (void)in_sizes; (void)n_in; (void)out_size; (void)ws_size;
  const float* x = (const float*)d_in[0];
  const float* Wq = (const float*)d_in[1];
  const float* Wk = (const float*)d_in[2];
  const float* Wv = (const float*)d_in[3];
  const float* Wp = (const float*)d_in[4];
  const float* gamma = (const float*)d_in[5];
  const float* beta = (const float*)d_in[6];
  char* ws = (char*)d_ws;
  short* xT = (short*)(ws + OFF_XT);
  short* Qn = (short*)(ws + OFF_QN);
  short* Kn = (short*)(ws + OFF_KN);
  short* Vt = (short*)(ws + OFF_VT);
  float* CI = (float*)(ws + OFF_CI);
  short* Wqb = (short*)(ws + OFF_WQ);
  short* Wkb = (short*)(ws + OFF_WK);
  short* Wvb = (short*)(ws + OFF_WV);
  short* Wpb = (short*)(ws + OFF_WP);
  float* S1 = (float*)(ws + OFF_S1);
  float* S2 = (float*)(ws + OFF_S2);
  float* AB = (float*)(ws + OFF_AB);
  float* P1 = (float*)(ws + OFF_P1);
  float* P2 = (float*)(ws + OFF_P2);
  short* yT = xT;            // reuse xT region (dead after projections)
  float* out = (float*)d_out;
  float* H = out;            // H staged in d_out; bn_apply rewrites in place

  hipMemsetAsync(S1, 0, 2048, stream);  // zero S1+S2

  dim3 blk(256);
  pack_w_kernel<<<dim3(256, 4), blk, 0, stream>>>(Wq, Wk, Wv, Wp, Wqb, Wkb, Wvb, Wpb);
  transpose_x_kernel<<<dim3(32, 4, 16), blk, 0, stream>>>(x, xT);
  proj_kernel<true><<<dim3(32, 16, 1), blk, 0, stream>>>(xT, Wqb, Qn, 64);
  proj_kernel<true><<<dim3(32, 16, 1), blk, 0, stream>>>(xT, Wkb, Kn, 64);
  proj_kernel<false><<<dim3(32, 16, 4), blk, 0, stream>>>(xT, Wvb, Vt, 256);
  colstats_kernel<<<dim3(32, 16), blk, 0, stream>>>(Qn, Kn, CI);
  attn_fsa_kernel<<<dim3(32, 16), blk, 0, stream>>>(x, Qn, Kn, Vt, CI, yT);
  wp_kernel<<<dim3(32, 16, 4), blk, 0, stream>>>(yT, Wpb, H, P1, P2);
  bn_reduce_kernel<<<dim3(32), blk, 0, stream>>>(P1, P2, S1, S2);
  bn_final_kernel<<<1, 256, 0, stream>>>(S1, S2, gamma, beta, AB);
  bn_apply_kernel<<<dim3(8192), blk, 0, stream>>>(H, x, AB, out);
}

// Round 7
// 301.793 us; speedup vs baseline: 3.3962x; 1.3429x over previous
//
#include <hip/hip_runtime.h>
#include <math.h>

#define B_ 16
#define C_ 256
#define N_ 2048
#define D_ 64
#define NP_ 2080  // Vt row pitch (shorts): 2048+32 breaks 4KB power-of-2 channel stride

typedef __attribute__((ext_vector_type(8))) short bf8;  // 8 bf16 (4 VGPRs)
typedef __attribute__((ext_vector_type(4))) float f4;   // MFMA C/D

#define MFMA16(A, Bv, Cv) __builtin_amdgcn_mfma_f32_16x16x32_bf16(A, Bv, Cv, 0, 0, 0)

__device__ __forceinline__ short f2b(float f) {  // f32 -> bf16 RNE
  unsigned u = __float_as_uint(f);
  u = (u + 0x7fff + ((u >> 16) & 1)) >> 16;
  return (short)u;
}
__device__ __forceinline__ float b2f(short s) {
  return __uint_as_float(((unsigned)(unsigned short)s) << 16);
}

// ---------------- workspace layout (bytes), ~44 MB ----------------
static constexpr size_t OFF_XT = 0;                          // bf16 [B][N][C] 16 MB (later yT)
static constexpr size_t OFF_QN = (size_t)16 << 20;           // bf16 [B][N][64] 4 MB
static constexpr size_t OFF_KN = (size_t)20 << 20;           // bf16 [B][N][64] 4 MB
static constexpr size_t OFF_VT = (size_t)24 << 20;           // bf16 [B][C][NP_] 17.04 MB
static constexpr size_t OFF_CI = (size_t)42 << 20;           // f32 [B][N] 128 KB
static constexpr size_t OFF_WQ = OFF_CI + ((size_t)128 << 10);
static constexpr size_t OFF_WK = OFF_WQ + ((size_t)32 << 10);
static constexpr size_t OFF_WV = OFF_WK + ((size_t)32 << 10);
static constexpr size_t OFF_WP = OFF_WV + ((size_t)128 << 10);
static constexpr size_t OFF_S1 = OFF_WP + ((size_t)128 << 10);
static constexpr size_t OFF_S2 = OFF_S1 + 1024;
static constexpr size_t OFF_AB = OFF_S2 + 1024;
static constexpr size_t OFF_P1 = OFF_AB + 4096;              // f32 [512][256] 512 KB
static constexpr size_t OFF_P2 = OFF_P1 + ((size_t)512 << 10);

// ---------------- pack weights to bf16 ----------------
__global__ void pack_w_kernel(const float* __restrict__ q, const float* __restrict__ k,
                              const float* __restrict__ v, const float* __restrict__ p,
                              short* wq, short* wk, short* wv, short* wp) {
  int idx = blockIdx.x * 256 + threadIdx.x;
  int which = blockIdx.y;
  const float* s = which == 0 ? q : which == 1 ? k : which == 2 ? v : p;
  short* d = which == 0 ? wq : which == 1 ? wk : which == 2 ? wv : wp;
  int cnt = which < 2 ? 64 * 256 : 256 * 256;
  if (idx < cnt) d[idx] = f2b(s[idx]);
}

// ---------------- x [B][C][N] f32 -> xT [B][N][C] bf16 ----------------
__global__ __launch_bounds__(256) void transpose_x_kernel(const float* __restrict__ x,
                                                          short* __restrict__ xT) {
  __shared__ float t[64][65];
  const int b = blockIdx.z, c0 = blockIdx.y * 64, n0 = blockIdx.x * 64;
  const int tid = threadIdx.x;
  const float* xp = x + ((size_t)b * C_ + c0) * N_ + n0;
#pragma unroll
  for (int i = 0; i < 16; ++i) {
    int idx = tid + i * 256;
    int cl = idx >> 6, nl = idx & 63;
    t[cl][nl] = xp[(size_t)cl * N_ + nl];
  }
  __syncthreads();
  short* op = xT + ((size_t)b * N_ + n0) * C_ + c0;
#pragma unroll
  for (int i = 0; i < 8; ++i) {
    int idx = tid + i * 256;
    int nl = idx >> 5, cl2 = (idx & 31) * 2;
    ushort2 v;
    v.x = (unsigned short)f2b(t[cl2][nl]);
    v.y = (unsigned short)f2b(t[cl2 + 1][nl]);
    *(ushort2*)(op + (size_t)nl * C_ + cl2) = v;
  }
}

// ---------------- projection GEMM: out = W(OxC) . x[b]  (MFMA, no LDS) ----------------
// OUTT=true : out[b][n][O] (Qn/Kn, O=64); OUTT=false: out[b][o][NP_] (Vt, pitch NP_)
template <bool OUTT>
__global__ __launch_bounds__(256, 4) void proj_kernel(const short* __restrict__ xT,
                                                      const short* __restrict__ W,
                                                      short* __restrict__ out, const int O) {
  const int tid = threadIdx.x;
  const int wv = tid >> 6, lane = tid & 63;
  const int li = lane & 15, quad = lane >> 4;
  const int b = blockIdx.y, n0 = blockIdx.x * 64, o0 = blockIdx.z * 64;
  const int n = n0 + wv * 16 + li;
  const short* xrow = xT + ((size_t)b * N_ + n) * C_ + quad * 8;
  f4 acc[4] = {};
  for (int ks = 0; ks < 8; ++ks) {
    bf8 bfr = *(const bf8*)(xrow + ks * 32);
#pragma unroll
    for (int ot = 0; ot < 4; ++ot) {
      bf8 afr = *(const bf8*)(W + (size_t)(o0 + ot * 16 + li) * C_ + ks * 32 + quad * 8);
      acc[ot] = MFMA16(afr, bfr, acc[ot]);
    }
  }
  if (OUTT) {
#pragma unroll
    for (int ot = 0; ot < 4; ++ot) {
      short4 v = {f2b(acc[ot].x), f2b(acc[ot].y), f2b(acc[ot].z), f2b(acc[ot].w)};
      *(short4*)(out + ((size_t)b * N_ + n) * O + o0 + ot * 16 + quad * 4) = v;
    }
  } else {
#pragma unroll
    for (int ot = 0; ot < 4; ++ot) {
#pragma unroll
      for (int r = 0; r < 4; ++r) {
        out[((size_t)b * C_ + o0 + ot * 16 + quad * 4 + r) * NP_ + n] = f2b(acc[ot][r]);
      }
    }
  }
}

// ---------------- pass 1: cinv[b][m] = 1 / sum_n exp(energy[n][m]) ----------------
// Q staged in LDS per block (once), double-buffered; K strip per wave held in regs.
__global__ __launch_bounds__(256, 2) void colstats_kernel(const short* __restrict__ Qn,
                                                          const short* __restrict__ Kn,
                                                          float* __restrict__ cinv) {
  __shared__ short qS[2][64][72];
  const int tid = threadIdx.x;
  const int wv = tid >> 6, lane = tid & 63;
  const int li = lane & 15, quad = lane >> 4;
  const int b = blockIdx.y, m0 = blockIdx.x * 64;
  const short* krow = Kn + ((size_t)b * N_ + m0 + wv * 16 + li) * D_ + quad * 8;
  bf8 af0 = *(const bf8*)(krow);
  bf8 af1 = *(const bf8*)(krow + 32);
  const short* Qb = Qn + (size_t)b * N_ * D_;
  // stage chunk 0
#pragma unroll
  for (int j = 0; j < 2; ++j) {
    int idx = tid * 2 + j;
    int row = idx >> 3, c8 = (idx & 7) * 8;
    *(bf8*)&qS[0][row][c8] = *(const bf8*)(Qb + (size_t)row * D_ + c8);
  }
  __syncthreads();
  float csum[4] = {0.f, 0.f, 0.f, 0.f};
  for (int t = 0; t < 32; ++t) {
    if (t < 31) {
#pragma unroll
      for (int j = 0; j < 2; ++j) {
        int idx = tid * 2 + j;
        int row = idx >> 3, c8 = (idx & 7) * 8;
        *(bf8*)&qS[(t + 1) & 1][row][c8] =
            *(const bf8*)(Qb + (size_t)((t + 1) * 64 + row) * D_ + c8);
      }
    }
#pragma unroll
    for (int nt = 0; nt < 4; ++nt) {
      bf8 b0 = *(const bf8*)&qS[t & 1][nt * 16 + li][quad * 8];
      bf8 b1 = *(const bf8*)&qS[t & 1][nt * 16 + li][32 + quad * 8];
      f4 s = {};
      s = MFMA16(af0, b0, s);
      s = MFMA16(af1, b1, s);
      csum[0] += __expf(s.x);
      csum[1] += __expf(s.y);
      csum[2] += __expf(s.z);
      csum[3] += __expf(s.w);
    }
    __syncthreads();
  }
#pragma unroll
  for (int r = 0; r < 4; ++r) {
#pragma unroll
    for (int m = 1; m < 16; m <<= 1) csum[r] += __shfl_xor(csum[r], m);
  }
  if (li == 0) {
#pragma unroll
    for (int r = 0; r < 4; ++r)
      cinv[(size_t)b * N_ + m0 + wv * 16 + quad * 4 + r] = 1.f / csum[r];
  }
}

// ---------------- pass 2: attention + fsa + y = x - fsa (-> yT bf16) ----------------
// 512 thr, n-tile 128, m-iter 128. S phase: m-split (wave wv owns m-strip wv*16,
// K tile loaded exactly once/block). PV phase: o-split (wave owns 32 o, V tile
// loaded exactly once/block). Pipelined: epoch t = [prefetch K/V(t+1); PV(t);
// S(t+1)], 2 pT bufs, one barrier/epoch.
__global__ __launch_bounds__(512, 2) void attn_fsa_kernel(
    const float* __restrict__ x, const short* __restrict__ Qn, const short* __restrict__ Kn,
    const short* __restrict__ Vt, const float* __restrict__ cinv, short* __restrict__ yT) {
  __shared__ short pT[2][128][136];  // [buf][n][m], pitch 136
  __shared__ float civS[2048];
  __shared__ float racc[128];
  const int tid = threadIdx.x;
  const int wv = tid >> 6, lane = tid & 63;
  const int li = lane & 15, quad = lane >> 4;
  const int b = blockIdx.y, n0 = blockIdx.x * 128;
  // stage civ + zero racc
  *(float4*)(civS + tid * 4) = *(const float4*)(cinv + (size_t)b * N_ + tid * 4);
  if (tid < 128) racc[tid] = 0.f;
  // Q B-frags for all 8 n-tiles (held in regs for the whole kernel)
  bf8 q[8][2];
#pragma unroll
  for (int nt = 0; nt < 8; ++nt) {
    const short* qrow = Qn + ((size_t)b * N_ + n0 + nt * 16 + li) * D_ + quad * 8;
    q[nt][0] = *(const bf8*)(qrow);
    q[nt][1] = *(const bf8*)(qrow + 32);
  }
  __syncthreads();
  f4 acc[2][8] = {};     // [ot][nt]: o = wv*32+ot*16+quad*4+r, n = n0+nt*16+li
  float rloc[8] = {};    // per-lane partial row sums, per nt
  const int ob = wv * 32;
  const short* Kb = Kn + (size_t)b * N_ * D_;
  const short* Vb = Vt + (size_t)b * C_ * NP_;
  // ---- prologue: S(0) -> buf0 ----
  {
    const short* krow = Kb + (size_t)(wv * 16 + li) * D_ + quad * 8;
    bf8 a0 = *(const bf8*)(krow);
    bf8 a1 = *(const bf8*)(krow + 32);
    f4 civ4 = *(const f4*)(civS + wv * 16 + quad * 4);
#pragma unroll
    for (int nt = 0; nt < 8; ++nt) {
      f4 s = {};
      s = MFMA16(a0, q[nt][0], s);
      s = MFMA16(a1, q[nt][1], s);
      short4 pv;
#pragma unroll
      for (int r = 0; r < 4; ++r) {
        float p = __expf(s[r]) * civ4[r];
        short ph = f2b(p);
        ((short*)&pv)[r] = ph;
        rloc[nt] += b2f(ph);
      }
      *(short4*)&pT[0][nt * 16 + li][wv * 16 + quad * 4] = pv;
    }
  }
  // ---- V(0) prefetch ----
  bf8 va[2][4];
#pragma unroll
  for (int ot = 0; ot < 2; ++ot)
#pragma unroll
    for (int kf = 0; kf < 4; ++kf)
      va[ot][kf] = *(const bf8*)(Vb + (size_t)(ob + ot * 16 + li) * NP_ + kf * 32 + quad * 8);
  __syncthreads();
  for (int t = 0; t < 16; ++t) {
    const int mm2 = (t + 1) * 128;
    bf8 vn[2][4], a0, a1;
    if (t < 15) {
#pragma unroll
      for (int ot = 0; ot < 2; ++ot)
#pragma unroll
        for (int kf = 0; kf < 4; ++kf)
          vn[ot][kf] = *(const bf8*)(Vb + (size_t)(ob + ot * 16 + li) * NP_ +
                                     mm2 + kf * 32 + quad * 8);
      const short* krow = Kb + (size_t)(mm2 + wv * 16 + li) * D_ + quad * 8;
      a0 = *(const bf8*)(krow);
      a1 = *(const bf8*)(krow + 32);
    }
    // ---- PV(t): reads pT[t&1] + va ----
    const short* Pb = &pT[t & 1][0][0];
#pragma unroll
    for (int nt = 0; nt < 8; ++nt) {
#pragma unroll
      for (int kf = 0; kf < 4; ++kf) {
        bf8 pb = *(const bf8*)(Pb + (size_t)(nt * 16 + li) * 136 + kf * 32 + quad * 8);
#pragma unroll
        for (int ot = 0; ot < 2; ++ot) acc[ot][nt] = MFMA16(va[ot][kf], pb, acc[ot][nt]);
      }
    }
    // ---- S(t+1): writes pT[(t+1)&1] ----
    if (t < 15) {
      f4 civ4 = *(const f4*)(civS + mm2 + wv * 16 + quad * 4);
      short* Pw = &pT[(t + 1) & 1][0][0];
#pragma unroll
      for (int nt = 0; nt < 8; ++nt) {
        f4 s = {};
        s = MFMA16(a0, q[nt][0], s);
        s = MFMA16(a1, q[nt][1], s);
        short4 pv;
#pragma unroll
        for (int r = 0; r < 4; ++r) {
          float p = __expf(s[r]) * civ4[r];
          short ph = f2b(p);
          ((short*)&pv)[r] = ph;
          rloc[nt] += b2f(ph);
        }
        *(short4*)(Pw + (size_t)(nt * 16 + li) * 136 + wv * 16 + quad * 4) = pv;
      }
#pragma unroll
      for (int ot = 0; ot < 2; ++ot)
#pragma unroll
        for (int kf = 0; kf < 4; ++kf) va[ot][kf] = vn[ot][kf];
    }
    __syncthreads();
  }
  // ---- row-sum reduction: quad-shfl then cross-wave LDS atomics ----
#pragma unroll
  for (int nt = 0; nt < 8; ++nt) {
    float rv = rloc[nt];
    rv += __shfl_xor(rv, 16);
    rv += __shfl_xor(rv, 32);
    if (quad == 0) atomicAdd(&racc[nt * 16 + li], rv);
  }
  __syncthreads();
  // ---- epilogue: y = x - fsa / rsum ----
#pragma unroll
  for (int nt = 0; nt < 8; ++nt) {
    const int nn = n0 + nt * 16 + li;
    const float rinv = 1.f / (1e-9f + racc[nt * 16 + li]);
    short* yrow = yT + ((size_t)b * N_ + nn) * C_ + ob;
#pragma unroll
    for (int ot = 0; ot < 2; ++ot) {
      short4 v;
#pragma unroll
      for (int r = 0; r < 4; ++r) {
        int o = ob + ot * 16 + quad * 4 + r;
        float xv = x[((size_t)b * C_ + o) * N_ + nn];
        ((short*)&v)[r] = f2b(xv - acc[ot][nt][r] * rinv);
      }
      *(short4*)(yrow + ot * 16 + quad * 4) = v;
    }
  }
}

// ---------------- h = Wp . y -> H (=d_out) f32 + per-block BN partials ----------------
__global__ __launch_bounds__(256, 4) void wp_kernel(const short* __restrict__ yT,
                                                    const short* __restrict__ Wp,
                                                    float* __restrict__ H,
                                                    float* __restrict__ P1,
                                                    float* __restrict__ P2) {
  __shared__ alignas(16) float ha[64][68];
  __shared__ float red1[64][4];
  __shared__ float red2[64][4];
  const int tid = threadIdx.x;
  const int wv = tid >> 6, lane = tid & 63;
  const int li = lane & 15, quad = lane >> 4;
  const int b = blockIdx.y, n0 = blockIdx.x * 64, o0 = blockIdx.z * 64;
  const int n = n0 + wv * 16 + li;
  const short* yrow = yT + ((size_t)b * N_ + n) * C_ + quad * 8;
  f4 acc[4] = {};
  for (int ks = 0; ks < 8; ++ks) {
    bf8 bfr = *(const bf8*)(yrow + ks * 32);
#pragma unroll
    for (int ot = 0; ot < 4; ++ot) {
      bf8 afr = *(const bf8*)(Wp + (size_t)(o0 + ot * 16 + li) * C_ + ks * 32 + quad * 8);
      acc[ot] = MFMA16(afr, bfr, acc[ot]);
    }
  }
#pragma unroll
  for (int ot = 0; ot < 4; ++ot)
#pragma unroll
    for (int r = 0; r < 4; ++r) ha[ot * 16 + quad * 4 + r][wv * 16 + li] = acc[ot][r];
  __syncthreads();
  const int o = tid >> 2, nq = tid & 3;
  float s1p = 0.f, s2p = 0.f;
  float* hrow = H + ((size_t)b * C_ + o0 + o) * N_ + n0 + nq * 16;
#pragma unroll
  for (int j4 = 0; j4 < 4; ++j4) {
    float4 v = *reinterpret_cast<const float4*>(&ha[o][nq * 16 + j4 * 4]);
    s1p += v.x + v.y + v.z + v.w;
    s2p += v.x * v.x + v.y * v.y + v.z * v.z + v.w * v.w;
    reinterpret_cast<float4*>(hrow)[j4] = v;
  }
  red1[o][nq] = s1p;
  red2[o][nq] = s2p;
  __syncthreads();
  if (tid < 64) {
    float a1 = red1[tid][0] + red1[tid][1] + red1[tid][2] + red1[tid][3];
    float a2 = red2[tid][0] + red2[tid][1] + red2[tid][2] + red2[tid][3];
    const int g = b * 32 + blockIdx.x;
    P1[(size_t)g * 256 + o0 + tid] = a1;
    P2[(size_t)g * 256 + o0 + tid] = a2;
  }
}

// ---------------- fold partials ----------------
__global__ __launch_bounds__(256) void bn_reduce_kernel(const float* __restrict__ P1,
                                                        const float* __restrict__ P2,
                                                        float* __restrict__ S1,
                                                        float* __restrict__ S2) {
  const int c = threadIdx.x;
  float a1 = 0.f, a2 = 0.f;
#pragma unroll
  for (int k = 0; k < 16; ++k) {
    int g = blockIdx.x * 16 + k;
    a1 += P1[(size_t)g * 256 + c];
    a2 += P2[(size_t)g * 256 + c];
  }
  atomicAdd(&S1[c], a1);
  atomicAdd(&S2[c], a2);
}

// ---------------- BN finalize + fused epilogue ----------------
__global__ void bn_final_kernel(const float* __restrict__ s1, const float* __restrict__ s2,
                                const float* __restrict__ gamma, const float* __restrict__ beta,
                                float* __restrict__ AB) {
  int o = threadIdx.x;
  const float invn = 1.f / ((float)B_ * N_);
  float mean = s1[o] * invn;
  float var = s2[o] * invn - mean * mean;
  float inv = rsqrtf(var + 1e-5f);
  float A = gamma[o] * inv;
  AB[o] = A;
  AB[256 + o] = beta[o] - mean * A;
}

__global__ __launch_bounds__(256) void bn_apply_kernel(const float* __restrict__ H,
                                                       const float* __restrict__ x,
                                                       const float* __restrict__ AB,
                                                       float* __restrict__ out) {
  size_t idx = ((size_t)blockIdx.x * 256 + threadIdx.x) * 4;
  int o = (int)((idx >> 11) & 255);
  float a = AB[o], c = AB[256 + o];
  float4 h = *reinterpret_cast<const float4*>(&H[idx]);
  float4 xv = *reinterpret_cast<const float4*>(&x[idx]);
  float4 r;
  r.x = fmaxf(h.x * a + c, 0.f) + xv.x;
  r.y = fmaxf(h.y * a + c, 0.f) + xv.y;
  r.z = fmaxf(h.z * a + c, 0.f) + xv.z;
  r.w = fmaxf(h.w * a + c, 0.f) + xv.w;
  *reinterpret_cast<float4*>(&out[idx]) = r;
}

extern "C" void kernel_launch(void* const* d_in, const int* in_sizes, int n_in,
                              void* d_out, int out_size, void* d_ws, size_t ws_size,
                              hipStream_t stream) {
  (void)in_sizes; (void)n_in; (void)out_size; (void)ws_size;
  const float* x = (const float*)d_in[0];
  const float* Wq = (const float*)d_in[1];
  const float* Wk = (const float*)d_in[2];
  const float* Wv = (const float*)d_in[3];
  const float* Wp = (const float*)d_in[4];
  const float* gamma = (const float*)d_in[5];
  const float* beta = (const float*)d_in[6];
  char* ws = (char*)d_ws;
  short* xT = (short*)(ws + OFF_XT);
  short* Qn = (short*)(ws + OFF_QN);
  short* Kn = (short*)(ws + OFF_KN);
  short* Vt = (short*)(ws + OFF_VT);
  float* CI = (float*)(ws + OFF_CI);
  short* Wqb = (short*)(ws + OFF_WQ);
  short* Wkb = (short*)(ws + OFF_WK);
  short* Wvb = (short*)(ws + OFF_WV);
  short* Wpb = (short*)(ws + OFF_WP);
  float* S1 = (float*)(ws + OFF_S1);
  float* S2 = (float*)(ws + OFF_S2);
  float* AB = (float*)(ws + OFF_AB);
  float* P1 = (float*)(ws + OFF_P1);
  float* P2 = (float*)(ws + OFF_P2);
  short* yT = xT;            // reuse xT region (dead after projections)
  float* out = (float*)d_out;
  float* H = out;            // H staged in d_out; bn_apply rewrites in place

  hipMemsetAsync(S1, 0, 2048, stream);  // zero S1+S2

  dim3 blk(256);
  pack_w_kernel<<<dim3(256, 4), blk, 0, stream>>>(Wq, Wk, Wv, Wp, Wqb, Wkb, Wvb, Wpb);
  transpose_x_kernel<<<dim3(32, 4, 16), blk, 0, stream>>>(x, xT);
  proj_kernel<true><<<dim3(32, 16, 1), blk, 0, stream>>>(xT, Wqb, Qn, 64);
  proj_kernel<true><<<dim3(32, 16, 1), blk, 0, stream>>>(xT, Wkb, Kn, 64);
  proj_kernel<false><<<dim3(32, 16, 4), blk, 0, stream>>>(xT, Wvb, Vt, 256);
  colstats_kernel<<<dim3(32, 16), blk, 0, stream>>>(Qn, Kn, CI);
  attn_fsa_kernel<<<dim3(16, 16), dim3(512), 0, stream>>>(x, Qn, Kn, Vt, CI, yT);
  wp_kernel<<<dim3(32, 16, 4), blk, 0, stream>>>(yT, Wpb, H, P1, P2);
  bn_reduce_kernel<<<dim3(32), blk, 0, stream>>>(P1, P2, S1, S2);
  bn_final_kernel<<<1, 256, 0, stream>>>(S1, S2, gamma, beta, AB);
  bn_apply_kernel<<<dim3(8192), blk, 0, stream>>>(H, x, AB, out);
}